// Round 1
// baseline (515.728 us; speedup 1.0000x reference)
//
#include <hip/hip_runtime.h>

// ---------------- problem constants ----------------
#define BATCH     32
#define T_SAMP    480000
#define NFRAMES   2998
#define KLEN      400
#define KA        416             // 13*32 ; k 400..415 zero-padded
#define NMEL      80
#define EPS_F     1.1920928955078125e-07f
#define SCALE2    1073741824.0f   // 32768^2, re-applied before log (A unscaled)
#define SPLIT_S   2048.0f         // lo-plane scale (keeps lo in fp16 normal range)
#define SPLIT_INV 4.8828125e-4f   // 1/2048
#define MTS       260             // melfT row stride (floats)

typedef _Float16 f16x8 __attribute__((ext_vector_type(8)));
typedef float    f32x4 __attribute__((ext_vector_type(4)));

// ---------------- kernel 0: zero the means accumulator ----------------
__global__ __launch_bounds__(256) void FbankWrapper_14285061226526_kernel(float* means)
{
    int i = blockIdx.x * 256 + threadIdx.x;
    if (i < BATCH * NMEL) means[i] = 0.f;
}

// ---------------- kernel 1: mel filter transpose + per-mel bin ranges ----------
__global__ __launch_bounds__(256) void k_setup(const float* __restrict__ melf,
                                               int* __restrict__ mlo,
                                               int* __restrict__ mhi,
                                               float* __restrict__ melfT)
{
    int m = threadIdx.x;
    if (m < NMEL) {
        int lo = 256, hi = 0;
        for (int k = 0; k < 257; ++k) {
            float w = melf[(size_t)k * NMEL + m];
            melfT[(size_t)m * MTS + k] = w;
            if (w > 0.f) { if (k < lo) lo = k; hi = k + 1; }
        }
        mlo[m] = lo;
        mhi[m] = hi;
    }
}

// ---------------- kernel 2: fused prep + split-fp16 MFMA DFT + spectrum + mel ----
// one block = 32 frames. A = Ah + Al/2048 (fp16 planes, LDS-resident, full K).
// B read from dcos/dsin global (L2-hot) and split in registers per k-step.
// C = Ah*Bh + (Ah*Bl + Al*Bh)/2048  (3 accumulator sets, fp32).
// K-loop is barrier-free; barriers only around the per-pass Sp round-trip.
__global__ __launch_bounds__(256) void k_main(const float* __restrict__ wav,
                                              const float* __restrict__ window,
                                              const float* __restrict__ melfT,
                                              const int* __restrict__ mlo,
                                              const int* __restrict__ mhi,
                                              const float* __restrict__ dcos,
                                              const float* __restrict__ dsin,
                                              float* __restrict__ out)
{
    __shared__ __align__(16) _Float16 Ah[32][424];   // 27,136 B
    __shared__ __align__(16) _Float16 Al[32][424];   // 27,136 B
    __shared__ __align__(16) float    Sp[32][66];    //  8,448 B  (62,720 total)

    const int tid  = threadIdx.x;
    const int lane = tid & 63;
    const int wid  = tid >> 6;
    const int tile = blockIdx.x;            // 0..2997

    // ---- prep: 8 threads per frame; mean via 8-lane shuffle; split to hi/lo ----
    {
        int fr = tid >> 3, og = tid & 7;
        int fb = tile * 32 + fr;
        int b  = fb / NFRAMES;
        int f  = fb - b * NFRAMES;
        const float* sig = wav + (size_t)b * T_SAMP + (size_t)f * 160;

        float s = 0.f;
        #pragma unroll
        for (int i = 0; i < 7; ++i) {
            int k0 = og * 8 + 64 * i;
            if (k0 < KLEN) {
                float4 x0 = *(const float4*)(sig + k0);
                float4 x1 = *(const float4*)(sig + k0 + 4);
                s += x0.x + x0.y + x0.z + x0.w + x1.x + x1.y + x1.z + x1.w;
            }
        }
        s += __shfl_xor(s, 1);
        s += __shfl_xor(s, 2);
        s += __shfl_xor(s, 4);
        float mean = s * (1.0f / (float)KLEN);

        #pragma unroll
        for (int i = 0; i < 7; ++i) {
            int k0 = og * 8 + 64 * i;
            if (k0 < KA) {
                f16x8 hv, lv;
                if (k0 < KLEN) {
                    float4 x0 = *(const float4*)(sig + k0);
                    float4 x1 = *(const float4*)(sig + k0 + 4);
                    float4 w0 = *(const float4*)(window + k0);
                    float4 w1 = *(const float4*)(window + k0 + 4);
                    float xm1 = (k0 > 0) ? sig[k0 - 1] : x0.x;
                    float xs[8] = {x0.x, x0.y, x0.z, x0.w, x1.x, x1.y, x1.z, x1.w};
                    float wv[8] = {w0.x, w0.y, w0.z, w0.w, w1.x, w1.y, w1.z, w1.w};
                    #pragma unroll
                    for (int j = 0; j < 8; ++j) {
                        float xp = (j == 0) ? xm1 : xs[j - 1];
                        float y  = (xs[j] - 0.97f * xp - 0.03f * mean) * wv[j];
                        _Float16 h = (_Float16)y;
                        hv[j] = h;
                        lv[j] = (_Float16)((y - (float)h) * SPLIT_S);
                    }
                } else {
                    #pragma unroll
                    for (int j = 0; j < 8; ++j) { hv[j] = (_Float16)0.f; lv[j] = (_Float16)0.f; }
                }
                *(f16x8*)&Ah[fr][k0] = hv;
                *(f16x8*)&Al[fr][k0] = lv;
            }
        }
    }
    __syncthreads();                        // A planes ready

    const int wn = wid;                     // wave -> 32-col strip
    const int q  = lane >> 4, lr = lane & 15;
    const int mf = tid & 31;                // mel: frame
    const int mg = tid >> 5;                // mel: 0..7 (mels mg, mg+8, ..., mg+72)

    int lo10[10], hi10[10];
    #pragma unroll
    for (int t = 0; t < 10; ++t) { lo10[t] = mlo[mg + 8 * t]; hi10[t] = mhi[mg + 8 * t]; }

    float accm[10];
    #pragma unroll
    for (int t = 0; t < 10; ++t) accm[t] = 0.f;

    for (int n0 = 0; n0 < 512; n0 += 128) {
        f32x4 aM[2][2], aX[2][2], aY[2][2];
        #pragma unroll
        for (int mt = 0; mt < 2; ++mt)
            #pragma unroll
            for (int nt = 0; nt < 2; ++nt) {
                aM[mt][nt] = (f32x4){0.f, 0.f, 0.f, 0.f};
                aX[mt][nt] = (f32x4){0.f, 0.f, 0.f, 0.f};
                aY[mt][nt] = (f32x4){0.f, 0.f, 0.f, 0.f};
            }

        // per-lane B row pointers (col n, k-chunk q)
        const float* bp[2];
        #pragma unroll
        for (int nt = 0; nt < 2; ++nt) {
            int n = n0 + wn * 32 + nt * 16 + lr;
            bp[nt] = ((n & 1) ? dsin : dcos) + (size_t)(n >> 1) * 512 + q * 8;
        }

        // ---- barrier-free K loop: LDS A-frags, global B + register split ----
        for (int kk = 0; kk < KA; kk += 32) {
            f16x8 ah[2], al[2], bh[2], bl[2];
            #pragma unroll
            for (int mt = 0; mt < 2; ++mt) {
                ah[mt] = *(const f16x8*)&Ah[mt * 16 + lr][kk + q * 8];
                al[mt] = *(const f16x8*)&Al[mt * 16 + lr][kk + q * 8];
            }
            #pragma unroll
            for (int nt = 0; nt < 2; ++nt) {
                float4 b0 = *(const float4*)(bp[nt] + kk);
                float4 b1 = *(const float4*)(bp[nt] + kk + 4);
                float bv[8] = {b0.x, b0.y, b0.z, b0.w, b1.x, b1.y, b1.z, b1.w};
                #pragma unroll
                for (int j = 0; j < 8; ++j) {
                    _Float16 h = (_Float16)bv[j];
                    bh[nt][j] = h;
                    bl[nt][j] = (_Float16)((bv[j] - (float)h) * SPLIT_S);
                }
            }
            #pragma unroll
            for (int mt = 0; mt < 2; ++mt)
                #pragma unroll
                for (int nt = 0; nt < 2; ++nt) {
                    aM[mt][nt] = __builtin_amdgcn_mfma_f32_16x16x32_f16(
                        ah[mt], bh[nt], aM[mt][nt], 0, 0, 0);
                    aX[mt][nt] = __builtin_amdgcn_mfma_f32_16x16x32_f16(
                        ah[mt], bl[nt], aX[mt][nt], 0, 0, 0);
                    aY[mt][nt] = __builtin_amdgcn_mfma_f32_16x16x32_f16(
                        al[mt], bh[nt], aY[mt][nt], 0, 0, 0);
                }
        }

        // ---- spectrum epilogue: combine splits, pair re/im via shfl ----
        __syncthreads();                    // prior pass's mel Sp-reads done
        #pragma unroll
        for (int mt = 0; mt < 2; ++mt)
            #pragma unroll
            for (int nt = 0; nt < 2; ++nt)
                #pragma unroll
                for (int r = 0; r < 4; ++r) {
                    float v = aM[mt][nt][r]
                            + (aX[mt][nt][r] + aY[mt][nt][r]) * SPLIT_INV;
                    float o = __shfl_xor(v, 1);
                    if ((lane & 1) == 0) {
                        int row = mt * 16 + q * 4 + r;               // frame 0..31
                        int bin = (wn * 32 + nt * 16 + lr) >> 1;     // 0..63
                        Sp[row][bin] = v * v + o * o;
                    }
                }
        __syncthreads();                    // Sp visible

        // ---- sparse mel: per-mel contiguous bin ranges ∩ this pass ----
        int kb0 = n0 >> 1;
        #pragma unroll
        for (int t = 0; t < 10; ++t) {
            int ks = lo10[t] > kb0 ? lo10[t] : kb0;
            int ke = hi10[t] < kb0 + 64 ? hi10[t] : kb0 + 64;
            const float* wrow = melfT + (size_t)(mg + 8 * t) * MTS;
            for (int k = ks; k < ke; ++k)
                accm[t] += Sp[mf][k - kb0] * wrow[k];
        }
    }

    // ---- re-apply 32768^2, log, fp32 store ----
    {
        size_t row = (size_t)tile * 32 + mf;
        #pragma unroll
        for (int t = 0; t < 10; ++t)
            out[row * NMEL + mg + 8 * t] = logf(fmaxf(accm[t] * SCALE2, EPS_F));
    }
}

// ---------------- kernel 3: per-(batch,mel) sums over frames (fp32) ----------
__global__ __launch_bounds__(256) void k_mean(const float* __restrict__ out,
                                              float* __restrict__ means)
{
    __shared__ float red[240];
    int b = blockIdx.y, tid = threadIdx.x;
    int f0   = blockIdx.x * 375;
    int fend = min(f0 + 375, NFRAMES);
    int r = tid / 80, m = tid - r * 80;
    if (tid < 240) {
        float s = 0.f;
        const float* base = out + (size_t)b * NFRAMES * NMEL;
        for (int f = f0 + r; f < fend; f += 3)
            s += base[(size_t)f * NMEL + m];
        red[tid] = s;
    }
    __syncthreads();
    if (tid < 80)
        atomicAdd(&means[b * NMEL + tid], red[tid] + red[tid + 80] + red[tid + 160]);
}

// ---------------- kernel 4: subtract mean in-place (fp32) ----------
__global__ __launch_bounds__(256) void k_norm(const float* __restrict__ means,
                                              float* __restrict__ out)
{
    const int PER = NFRAMES * NMEL;           // 239,840
    int b = blockIdx.y;
    int e = blockIdx.x * 256 + threadIdx.x;
    if (e < PER) {
        int m = e % NMEL;
        size_t idx = (size_t)b * PER + e;
        out[idx] = out[idx] - means[b * NMEL + m] * (1.0f / (float)NFRAMES);
    }
}

// ---------------- launch ----------------
extern "C" void kernel_launch(void* const* d_in, const int* in_sizes, int n_in,
                              void* d_out, int out_size, void* d_ws, size_t ws_size,
                              hipStream_t stream)
{
    const float* wav    = (const float*)d_in[0];
    const float* window = (const float*)d_in[1];
    const float* melf   = (const float*)d_in[2];
    const float* dcos   = (const float*)d_in[3];
    const float* dsin   = (const float*)d_in[4];
    float* out = (float*)d_out;

    // ws layout (94,080 B total; round-6 proved >= 436 KB usable):
    //   means fp32 32*80   @ 0        (10,240)
    //   mlo   int  80      @ 10,240   (320)
    //   mhi   int  80      @ 10,560   (320)
    //   melfT fp32 80*260  @ 10,880   (83,200)
    char* ws = (char*)d_ws;
    float* means = (float*)ws;
    int*   mlo   = (int*)(ws + 10240);
    int*   mhi   = (int*)(ws + 10560);
    float* melfT = (float*)(ws + 10880);

    FbankWrapper_14285061226526_kernel<<<10, 256, 0, stream>>>(means);
    k_setup<<<1, 256, 0, stream>>>(melf, mlo, mhi, melfT);
    k_main<<<2998, 256, 0, stream>>>(wav, window, melfT, mlo, mhi, dcos, dsin, out);
    k_mean<<<dim3(8, BATCH), 256, 0, stream>>>(out, means);
    k_norm<<<dim3((NFRAMES * NMEL + 255) / 256, BATCH), 256, 0, stream>>>(means, out);
}

// Round 2
// 412.021 us; speedup vs baseline: 1.2517x; 1.2517x over previous
//
#include <hip/hip_runtime.h>

// ---------------- problem constants ----------------
#define BATCH     32
#define T_SAMP    480000
#define NFRAMES   2998
#define KLEN      400
#define KA        416             // 13*32 ; k 400..415 zero-padded
#define NMEL      80
#define EPS_F     1.1920928955078125e-07f
#define SCALE2    1073741824.0f   // 32768^2, re-applied before log (A unscaled)
#define SPLIT_S   2048.0f         // lo-plane scale (keeps lo in fp16 normal range)
#define SPLIT_INV 4.8828125e-4f   // 1/2048
#define MTS       260             // melfT row stride (floats)

typedef _Float16 f16x8 __attribute__((ext_vector_type(8)));
typedef float    f32x4 __attribute__((ext_vector_type(4)));

// ---------------- kernel 0: zero the means accumulator ----------------
__global__ __launch_bounds__(256) void FbankWrapper_14285061226526_kernel(float* means)
{
    int i = blockIdx.x * 256 + threadIdx.x;
    if (i < BATCH * NMEL) means[i] = 0.f;
}

// ---------------- kernel 1: mel filter transpose + per-mel bin ranges ----------
__global__ __launch_bounds__(256) void k_setup(const float* __restrict__ melf,
                                               int* __restrict__ mlo,
                                               int* __restrict__ mhi,
                                               float* __restrict__ melfT)
{
    int m = threadIdx.x;
    if (m < NMEL) {
        int lo = 256, hi = 0;
        for (int k = 0; k < 257; ++k) {
            float w = melf[(size_t)k * NMEL + m];
            melfT[(size_t)m * MTS + k] = w;
            if (w > 0.f) { if (k < lo) lo = k; hi = k + 1; }
        }
        mlo[m] = lo;
        mhi[m] = hi;
    }
}

// ---------------- kernel 1b: pre-split DFT basis into fp16 hi/lo planes -------
// Layout: Bh/Bl[col n][k], n = 0..511 (re/im interleaved: col n -> row n>>1 of
// dcos (n even) / dsin (n odd)), k = 0..415.  Same cvt ops as the old
// in-register split -> bit-identical MFMA inputs.
__global__ __launch_bounds__(256) void k_setupB(const float* __restrict__ dcos,
                                                const float* __restrict__ dsin,
                                                _Float16* __restrict__ Bh,
                                                _Float16* __restrict__ Bl)
{
    int e = (blockIdx.x * 256 + threadIdx.x) * 8;     // 512*416 elements
    if (e >= 512 * KA) return;
    int n = e / KA;
    int k = e - n * KA;                               // multiple of 8
    const float* src = ((n & 1) ? dsin : dcos) + (size_t)(n >> 1) * 512 + k;
    f16x8 hv, lv;
    #pragma unroll
    for (int j = 0; j < 8; ++j) {
        float v = src[j];
        _Float16 h = (_Float16)v;
        hv[j] = h;
        lv[j] = (_Float16)((v - (float)h) * SPLIT_S);
    }
    *(f16x8*)(Bh + e) = hv;
    *(f16x8*)(Bl + e) = lv;
}

// ---------------- kernel 2 (fast path): fused prep + MFMA DFT, pre-split B ----
// one block = 32 frames. A = Ah + Al/2048 (fp16 planes, LDS-resident, full K).
// B planes pre-split in workspace (L2-hot f16x8 loads, zero conversion VALU).
// C = Ah*Bh + (Ah*Bl + Al*Bh)/2048  (3 accumulator sets, fp32).
__global__ __launch_bounds__(256) void k_main_pre(const float* __restrict__ wav,
                                                  const float* __restrict__ window,
                                                  const float* __restrict__ melfT,
                                                  const int* __restrict__ mlo,
                                                  const int* __restrict__ mhi,
                                                  const _Float16* __restrict__ Bh,
                                                  const _Float16* __restrict__ Bl,
                                                  float* __restrict__ out)
{
    __shared__ __align__(16) _Float16 Ah[32][424];   // 27,136 B
    __shared__ __align__(16) _Float16 Al[32][424];   // 27,136 B
    __shared__ __align__(16) float    Sp[32][66];    //  8,448 B  (62,720 total)

    const int tid  = threadIdx.x;
    const int lane = tid & 63;
    const int wid  = tid >> 6;
    const int tile = blockIdx.x;            // 0..2997

    // ---- prep: 8 threads per frame; mean via 8-lane shuffle; split to hi/lo ----
    {
        int fr = tid >> 3, og = tid & 7;
        int fb = tile * 32 + fr;
        int b  = fb / NFRAMES;
        int f  = fb - b * NFRAMES;
        const float* sig = wav + (size_t)b * T_SAMP + (size_t)f * 160;

        float s = 0.f;
        #pragma unroll
        for (int i = 0; i < 7; ++i) {
            int k0 = og * 8 + 64 * i;
            if (k0 < KLEN) {
                float4 x0 = *(const float4*)(sig + k0);
                float4 x1 = *(const float4*)(sig + k0 + 4);
                s += x0.x + x0.y + x0.z + x0.w + x1.x + x1.y + x1.z + x1.w;
            }
        }
        s += __shfl_xor(s, 1);
        s += __shfl_xor(s, 2);
        s += __shfl_xor(s, 4);
        float mean = s * (1.0f / (float)KLEN);

        #pragma unroll
        for (int i = 0; i < 7; ++i) {
            int k0 = og * 8 + 64 * i;
            if (k0 < KA) {
                f16x8 hv, lv;
                if (k0 < KLEN) {
                    float4 x0 = *(const float4*)(sig + k0);
                    float4 x1 = *(const float4*)(sig + k0 + 4);
                    float4 w0 = *(const float4*)(window + k0);
                    float4 w1 = *(const float4*)(window + k0 + 4);
                    float xm1 = (k0 > 0) ? sig[k0 - 1] : x0.x;
                    float xs[8] = {x0.x, x0.y, x0.z, x0.w, x1.x, x1.y, x1.z, x1.w};
                    float wv[8] = {w0.x, w0.y, w0.z, w0.w, w1.x, w1.y, w1.z, w1.w};
                    #pragma unroll
                    for (int j = 0; j < 8; ++j) {
                        float xp = (j == 0) ? xm1 : xs[j - 1];
                        float y  = (xs[j] - 0.97f * xp - 0.03f * mean) * wv[j];
                        _Float16 h = (_Float16)y;
                        hv[j] = h;
                        lv[j] = (_Float16)((y - (float)h) * SPLIT_S);
                    }
                } else {
                    #pragma unroll
                    for (int j = 0; j < 8; ++j) { hv[j] = (_Float16)0.f; lv[j] = (_Float16)0.f; }
                }
                *(f16x8*)&Ah[fr][k0] = hv;
                *(f16x8*)&Al[fr][k0] = lv;
            }
        }
    }
    __syncthreads();                        // A planes ready

    const int wn = wid;                     // wave -> 32-col strip
    const int q  = lane >> 4, lr = lane & 15;
    const int mf = tid & 31;                // mel: frame
    const int mg = tid >> 5;                // mel: 0..7 (mels mg, mg+8, ..., mg+72)

    int lo10[10], hi10[10];
    #pragma unroll
    for (int t = 0; t < 10; ++t) { lo10[t] = mlo[mg + 8 * t]; hi10[t] = mhi[mg + 8 * t]; }

    float accm[10];
    #pragma unroll
    for (int t = 0; t < 10; ++t) accm[t] = 0.f;

    for (int n0 = 0; n0 < 512; n0 += 128) {
        f32x4 aM[2][2], aX[2][2], aY[2][2];
        #pragma unroll
        for (int mt = 0; mt < 2; ++mt)
            #pragma unroll
            for (int nt = 0; nt < 2; ++nt) {
                aM[mt][nt] = (f32x4){0.f, 0.f, 0.f, 0.f};
                aX[mt][nt] = (f32x4){0.f, 0.f, 0.f, 0.f};
                aY[mt][nt] = (f32x4){0.f, 0.f, 0.f, 0.f};
            }

        // per-lane pre-split B fragment pointers (col n, k-chunk q)
        const _Float16* bhp[2];
        const _Float16* blp[2];
        #pragma unroll
        for (int nt = 0; nt < 2; ++nt) {
            int n = n0 + wn * 32 + nt * 16 + lr;
            size_t off = (size_t)n * KA + q * 8;
            bhp[nt] = Bh + off;
            blp[nt] = Bl + off;
        }

        // ---- barrier-free K loop: LDS A-frags, pre-split global B frags ----
        for (int kk = 0; kk < KA; kk += 32) {
            f16x8 ah[2], al[2], bh[2], bl[2];
            #pragma unroll
            for (int mt = 0; mt < 2; ++mt) {
                ah[mt] = *(const f16x8*)&Ah[mt * 16 + lr][kk + q * 8];
                al[mt] = *(const f16x8*)&Al[mt * 16 + lr][kk + q * 8];
            }
            #pragma unroll
            for (int nt = 0; nt < 2; ++nt) {
                bh[nt] = *(const f16x8*)(bhp[nt] + kk);
                bl[nt] = *(const f16x8*)(blp[nt] + kk);
            }
            #pragma unroll
            for (int mt = 0; mt < 2; ++mt)
                #pragma unroll
                for (int nt = 0; nt < 2; ++nt) {
                    aM[mt][nt] = __builtin_amdgcn_mfma_f32_16x16x32_f16(
                        ah[mt], bh[nt], aM[mt][nt], 0, 0, 0);
                    aX[mt][nt] = __builtin_amdgcn_mfma_f32_16x16x32_f16(
                        ah[mt], bl[nt], aX[mt][nt], 0, 0, 0);
                    aY[mt][nt] = __builtin_amdgcn_mfma_f32_16x16x32_f16(
                        al[mt], bh[nt], aY[mt][nt], 0, 0, 0);
                }
        }

        // ---- spectrum epilogue: combine splits, pair re/im via shfl ----
        __syncthreads();                    // prior pass's mel Sp-reads done
        #pragma unroll
        for (int mt = 0; mt < 2; ++mt)
            #pragma unroll
            for (int nt = 0; nt < 2; ++nt)
                #pragma unroll
                for (int r = 0; r < 4; ++r) {
                    float v = aM[mt][nt][r]
                            + (aX[mt][nt][r] + aY[mt][nt][r]) * SPLIT_INV;
                    float o = __shfl_xor(v, 1);
                    if ((lane & 1) == 0) {
                        int row = mt * 16 + q * 4 + r;               // frame 0..31
                        int bin = (wn * 32 + nt * 16 + lr) >> 1;     // 0..63
                        Sp[row][bin] = v * v + o * o;
                    }
                }
        __syncthreads();                    // Sp visible

        // ---- sparse mel: per-mel contiguous bin ranges ∩ this pass ----
        int kb0 = n0 >> 1;
        #pragma unroll
        for (int t = 0; t < 10; ++t) {
            int ks = lo10[t] > kb0 ? lo10[t] : kb0;
            int ke = hi10[t] < kb0 + 64 ? hi10[t] : kb0 + 64;
            const float* wrow = melfT + (size_t)(mg + 8 * t) * MTS;
            for (int k = ks; k < ke; ++k)
                accm[t] += Sp[mf][k - kb0] * wrow[k];
        }
    }

    // ---- re-apply 32768^2, log, fp32 store ----
    {
        size_t row = (size_t)tile * 32 + mf;
        #pragma unroll
        for (int t = 0; t < 10; ++t)
            out[row * NMEL + mg + 8 * t] = logf(fmaxf(accm[t] * SCALE2, EPS_F));
    }
}

// ---------------- kernel 2 (fallback): in-register B split (round-1 kernel) ---
__global__ __launch_bounds__(256) void k_main(const float* __restrict__ wav,
                                              const float* __restrict__ window,
                                              const float* __restrict__ melfT,
                                              const int* __restrict__ mlo,
                                              const int* __restrict__ mhi,
                                              const float* __restrict__ dcos,
                                              const float* __restrict__ dsin,
                                              float* __restrict__ out)
{
    __shared__ __align__(16) _Float16 Ah[32][424];
    __shared__ __align__(16) _Float16 Al[32][424];
    __shared__ __align__(16) float    Sp[32][66];

    const int tid  = threadIdx.x;
    const int lane = tid & 63;
    const int wid  = tid >> 6;
    const int tile = blockIdx.x;

    {
        int fr = tid >> 3, og = tid & 7;
        int fb = tile * 32 + fr;
        int b  = fb / NFRAMES;
        int f  = fb - b * NFRAMES;
        const float* sig = wav + (size_t)b * T_SAMP + (size_t)f * 160;

        float s = 0.f;
        #pragma unroll
        for (int i = 0; i < 7; ++i) {
            int k0 = og * 8 + 64 * i;
            if (k0 < KLEN) {
                float4 x0 = *(const float4*)(sig + k0);
                float4 x1 = *(const float4*)(sig + k0 + 4);
                s += x0.x + x0.y + x0.z + x0.w + x1.x + x1.y + x1.z + x1.w;
            }
        }
        s += __shfl_xor(s, 1);
        s += __shfl_xor(s, 2);
        s += __shfl_xor(s, 4);
        float mean = s * (1.0f / (float)KLEN);

        #pragma unroll
        for (int i = 0; i < 7; ++i) {
            int k0 = og * 8 + 64 * i;
            if (k0 < KA) {
                f16x8 hv, lv;
                if (k0 < KLEN) {
                    float4 x0 = *(const float4*)(sig + k0);
                    float4 x1 = *(const float4*)(sig + k0 + 4);
                    float4 w0 = *(const float4*)(window + k0);
                    float4 w1 = *(const float4*)(window + k0 + 4);
                    float xm1 = (k0 > 0) ? sig[k0 - 1] : x0.x;
                    float xs[8] = {x0.x, x0.y, x0.z, x0.w, x1.x, x1.y, x1.z, x1.w};
                    float wv[8] = {w0.x, w0.y, w0.z, w0.w, w1.x, w1.y, w1.z, w1.w};
                    #pragma unroll
                    for (int j = 0; j < 8; ++j) {
                        float xp = (j == 0) ? xm1 : xs[j - 1];
                        float y  = (xs[j] - 0.97f * xp - 0.03f * mean) * wv[j];
                        _Float16 h = (_Float16)y;
                        hv[j] = h;
                        lv[j] = (_Float16)((y - (float)h) * SPLIT_S);
                    }
                } else {
                    #pragma unroll
                    for (int j = 0; j < 8; ++j) { hv[j] = (_Float16)0.f; lv[j] = (_Float16)0.f; }
                }
                *(f16x8*)&Ah[fr][k0] = hv;
                *(f16x8*)&Al[fr][k0] = lv;
            }
        }
    }
    __syncthreads();

    const int wn = wid;
    const int q  = lane >> 4, lr = lane & 15;
    const int mf = tid & 31;
    const int mg = tid >> 5;

    int lo10[10], hi10[10];
    #pragma unroll
    for (int t = 0; t < 10; ++t) { lo10[t] = mlo[mg + 8 * t]; hi10[t] = mhi[mg + 8 * t]; }

    float accm[10];
    #pragma unroll
    for (int t = 0; t < 10; ++t) accm[t] = 0.f;

    for (int n0 = 0; n0 < 512; n0 += 128) {
        f32x4 aM[2][2], aX[2][2], aY[2][2];
        #pragma unroll
        for (int mt = 0; mt < 2; ++mt)
            #pragma unroll
            for (int nt = 0; nt < 2; ++nt) {
                aM[mt][nt] = (f32x4){0.f, 0.f, 0.f, 0.f};
                aX[mt][nt] = (f32x4){0.f, 0.f, 0.f, 0.f};
                aY[mt][nt] = (f32x4){0.f, 0.f, 0.f, 0.f};
            }

        const float* bp[2];
        #pragma unroll
        for (int nt = 0; nt < 2; ++nt) {
            int n = n0 + wn * 32 + nt * 16 + lr;
            bp[nt] = ((n & 1) ? dsin : dcos) + (size_t)(n >> 1) * 512 + q * 8;
        }

        for (int kk = 0; kk < KA; kk += 32) {
            f16x8 ah[2], al[2], bh[2], bl[2];
            #pragma unroll
            for (int mt = 0; mt < 2; ++mt) {
                ah[mt] = *(const f16x8*)&Ah[mt * 16 + lr][kk + q * 8];
                al[mt] = *(const f16x8*)&Al[mt * 16 + lr][kk + q * 8];
            }
            #pragma unroll
            for (int nt = 0; nt < 2; ++nt) {
                float4 b0 = *(const float4*)(bp[nt] + kk);
                float4 b1 = *(const float4*)(bp[nt] + kk + 4);
                float bv[8] = {b0.x, b0.y, b0.z, b0.w, b1.x, b1.y, b1.z, b1.w};
                #pragma unroll
                for (int j = 0; j < 8; ++j) {
                    _Float16 h = (_Float16)bv[j];
                    bh[nt][j] = h;
                    bl[nt][j] = (_Float16)((bv[j] - (float)h) * SPLIT_S);
                }
            }
            #pragma unroll
            for (int mt = 0; mt < 2; ++mt)
                #pragma unroll
                for (int nt = 0; nt < 2; ++nt) {
                    aM[mt][nt] = __builtin_amdgcn_mfma_f32_16x16x32_f16(
                        ah[mt], bh[nt], aM[mt][nt], 0, 0, 0);
                    aX[mt][nt] = __builtin_amdgcn_mfma_f32_16x16x32_f16(
                        ah[mt], bl[nt], aX[mt][nt], 0, 0, 0);
                    aY[mt][nt] = __builtin_amdgcn_mfma_f32_16x16x32_f16(
                        al[mt], bh[nt], aY[mt][nt], 0, 0, 0);
                }
        }

        __syncthreads();
        #pragma unroll
        for (int mt = 0; mt < 2; ++mt)
            #pragma unroll
            for (int nt = 0; nt < 2; ++nt)
                #pragma unroll
                for (int r = 0; r < 4; ++r) {
                    float v = aM[mt][nt][r]
                            + (aX[mt][nt][r] + aY[mt][nt][r]) * SPLIT_INV;
                    float o = __shfl_xor(v, 1);
                    if ((lane & 1) == 0) {
                        int row = mt * 16 + q * 4 + r;
                        int bin = (wn * 32 + nt * 16 + lr) >> 1;
                        Sp[row][bin] = v * v + o * o;
                    }
                }
        __syncthreads();

        int kb0 = n0 >> 1;
        #pragma unroll
        for (int t = 0; t < 10; ++t) {
            int ks = lo10[t] > kb0 ? lo10[t] : kb0;
            int ke = hi10[t] < kb0 + 64 ? hi10[t] : kb0 + 64;
            const float* wrow = melfT + (size_t)(mg + 8 * t) * MTS;
            for (int k = ks; k < ke; ++k)
                accm[t] += Sp[mf][k - kb0] * wrow[k];
        }
    }

    {
        size_t row = (size_t)tile * 32 + mf;
        #pragma unroll
        for (int t = 0; t < 10; ++t)
            out[row * NMEL + mg + 8 * t] = logf(fmaxf(accm[t] * SCALE2, EPS_F));
    }
}

// ---------------- kernel 3: per-(batch,mel) sums over frames (fp32) ----------
__global__ __launch_bounds__(256) void k_mean(const float* __restrict__ out,
                                              float* __restrict__ means)
{
    __shared__ float red[240];
    int b = blockIdx.y, tid = threadIdx.x;
    int f0   = blockIdx.x * 375;
    int fend = min(f0 + 375, NFRAMES);
    int r = tid / 80, m = tid - r * 80;
    if (tid < 240) {
        float s = 0.f;
        const float* base = out + (size_t)b * NFRAMES * NMEL;
        for (int f = f0 + r; f < fend; f += 3)
            s += base[(size_t)f * NMEL + m];
        red[tid] = s;
    }
    __syncthreads();
    if (tid < 80)
        atomicAdd(&means[b * NMEL + tid], red[tid] + red[tid + 80] + red[tid + 160]);
}

// ---------------- kernel 4: subtract mean in-place (fp32) ----------
__global__ __launch_bounds__(256) void k_norm(const float* __restrict__ means,
                                              float* __restrict__ out)
{
    const int PER = NFRAMES * NMEL;           // 239,840
    int b = blockIdx.y;
    int e = blockIdx.x * 256 + threadIdx.x;
    if (e < PER) {
        int m = e % NMEL;
        size_t idx = (size_t)b * PER + e;
        out[idx] = out[idx] - means[b * NMEL + m] * (1.0f / (float)NFRAMES);
    }
}

// ---------------- launch ----------------
extern "C" void kernel_launch(void* const* d_in, const int* in_sizes, int n_in,
                              void* d_out, int out_size, void* d_ws, size_t ws_size,
                              hipStream_t stream)
{
    const float* wav    = (const float*)d_in[0];
    const float* window = (const float*)d_in[1];
    const float* melf   = (const float*)d_in[2];
    const float* dcos   = (const float*)d_in[3];
    const float* dsin   = (const float*)d_in[4];
    float* out = (float*)d_out;

    // ws layout:
    //   means fp32 32*80   @ 0        (10,240)
    //   mlo   int  80      @ 10,240   (320)
    //   mhi   int  80      @ 10,560   (320)
    //   melfT fp32 80*260  @ 10,880   (83,200)   -> 94,080
    //   Bh    f16  512*416 @ 94,208   (425,984)  -> 520,192   [fast path only]
    //   Bl    f16  512*416 @ 520,192  (425,984)  -> 946,176
    char* ws = (char*)d_ws;
    float*     means = (float*)ws;
    int*       mlo   = (int*)(ws + 10240);
    int*       mhi   = (int*)(ws + 10560);
    float*     melfT = (float*)(ws + 10880);
    _Float16*  Bh    = (_Float16*)(ws + 94208);
    _Float16*  Bl    = (_Float16*)(ws + 520192);

    const bool pre = (ws_size >= 946176);

    FbankWrapper_14285061226526_kernel<<<10, 256, 0, stream>>>(means);
    k_setup<<<1, 256, 0, stream>>>(melf, mlo, mhi, melfT);
    if (pre) {
        k_setupB<<<(512 * KA / 8 + 255) / 256, 256, 0, stream>>>(dcos, dsin, Bh, Bl);
        k_main_pre<<<2998, 256, 0, stream>>>(wav, window, melfT, mlo, mhi, Bh, Bl, out);
    } else {
        k_main<<<2998, 256, 0, stream>>>(wav, window, melfT, mlo, mhi, dcos, dsin, out);
    }
    k_mean<<<dim3(8, BATCH), 256, 0, stream>>>(out, means);
    k_norm<<<dim3((NFRAMES * NMEL + 255) / 256, BATCH), 256, 0, stream>>>(means, out);
}

// Round 3
// 363.725 us; speedup vs baseline: 1.4179x; 1.1328x over previous
//
#include <hip/hip_runtime.h>

// ---------------- problem constants ----------------
#define BATCH     32
#define T_SAMP    480000
#define NFRAMES   2998
#define KLEN      400
#define KA        416             // 13*32 ; k 400..415 zero-padded
#define NMEL      80
#define EPS_F     1.1920928955078125e-07f
#define SCALE2    1073741824.0f   // 32768^2, re-applied before log (A unscaled)
#define SPLIT_S   2048.0f         // lo-plane scale (keeps lo in fp16 normal range)
#define SPLIT_INV 4.8828125e-4f   // 1/2048
#define MTS       260             // melfT row stride (floats)

typedef _Float16 f16x8 __attribute__((ext_vector_type(8)));
typedef float    f32x4 __attribute__((ext_vector_type(4)));

// ---------------- kernel 0: zero the means accumulator (name kept for harness) --
__global__ __launch_bounds__(256) void FbankWrapper_14285061226526_kernel(float* means)
{
    int i = blockIdx.x * 256 + threadIdx.x;
    if (i < BATCH * NMEL) means[i] = 0.f;
}

// ---------------- kernel 1: fused setup ----------------------------------------
// blocks 0..79   : melfT row m = transpose of melf col m (parallel over k),
//                  + per-mel lo/hi bin range via LDS atomics, + zero tail 257..259
// blocks 80..183 : pre-split DFT basis into fp16 hi/lo planes (gated on `pre`)
__global__ __launch_bounds__(256) void k_prep(const float* __restrict__ melf,
                                              const float* __restrict__ dcos,
                                              const float* __restrict__ dsin,
                                              int* __restrict__ mlo,
                                              int* __restrict__ mhi,
                                              float* __restrict__ melfT,
                                              _Float16* __restrict__ Bh,
                                              _Float16* __restrict__ Bl,
                                              int pre)
{
    const int bid = blockIdx.x;
    const int tid = threadIdx.x;

    if (bid < 80) {
        __shared__ int slo, shi;
        if (tid == 0) { slo = 256; shi = 0; }
        __syncthreads();
        const int m = bid;
        float w = melf[(size_t)tid * NMEL + m];
        melfT[(size_t)m * MTS + tid] = w;
        int lom = (w > 0.f) ? tid : 256;
        int him = (w > 0.f) ? tid + 1 : 0;
        if (tid == 0) {
            float w2 = melf[(size_t)256 * NMEL + m];
            melfT[(size_t)m * MTS + 256] = w2;
            if (w2 > 0.f) { lom = 256 < lom ? 256 : lom; him = 257; }
            melfT[(size_t)m * MTS + 257] = 0.f;
            melfT[(size_t)m * MTS + 258] = 0.f;
            melfT[(size_t)m * MTS + 259] = 0.f;
        }
        atomicMin(&slo, lom);
        atomicMax(&shi, him);
        __syncthreads();
        if (tid == 0) { mlo[m] = slo; mhi[m] = shi; }
        return;
    }

    if (!pre) return;
    // B split: layout Bh/Bl[col n][k], n re/im interleaved, k 0..415
    int e = ((bid - 80) * 256 + tid) * 8;
    if (e >= 512 * KA) return;
    int n = e / KA;
    int k = e - n * KA;
    const float* src = ((n & 1) ? dsin : dcos) + (size_t)(n >> 1) * 512 + k;
    f16x8 hv, lv;
    #pragma unroll
    for (int j = 0; j < 8; ++j) {
        float v = src[j];
        _Float16 h = (_Float16)v;
        hv[j] = h;
        lv[j] = (_Float16)((v - (float)h) * SPLIT_S);
    }
    *(f16x8*)(Bh + e) = hv;
    *(f16x8*)(Bl + e) = lv;
}

// ---------------- kernel 2 (fast path): pipelined split-fp16 MFMA DFT ----------
// one block = 32 frames. A planes LDS-resident; B planes pre-split in workspace.
// K-loop fully unrolled (13 steps): B regs triple-buffered (depth-2 prefetch),
// A regs double-buffered (depth-1). Merged correction accumulator:
// C = Ah*Bh + (Al*Bh + Ah*Bl)/2048 with aC accumulating both cross terms.
__global__ __launch_bounds__(256) void k_main_pre(const float* __restrict__ wav,
                                                  const float* __restrict__ window,
                                                  const float* __restrict__ melfT,
                                                  const int* __restrict__ mlo,
                                                  const int* __restrict__ mhi,
                                                  const _Float16* __restrict__ Bh,
                                                  const _Float16* __restrict__ Bl,
                                                  float* __restrict__ out)
{
    __shared__ __align__(16) _Float16 Ah[32][424];   // 27,136 B
    __shared__ __align__(16) _Float16 Al[32][424];   // 27,136 B
    __shared__ __align__(16) float    Sp[32][68];    //  8,704 B  (62,976 total)

    const int tid  = threadIdx.x;
    const int lane = tid & 63;
    const int wid  = tid >> 6;
    const int tile = blockIdx.x;            // 0..2997

    // ---- prep: 8 threads per frame; mean via 8-lane shuffle; split to hi/lo ----
    {
        int fr = tid >> 3, og = tid & 7;
        int fb = tile * 32 + fr;
        int b  = fb / NFRAMES;
        int f  = fb - b * NFRAMES;
        const float* sig = wav + (size_t)b * T_SAMP + (size_t)f * 160;

        float s = 0.f;
        #pragma unroll
        for (int i = 0; i < 7; ++i) {
            int k0 = og * 8 + 64 * i;
            if (k0 < KLEN) {
                float4 x0 = *(const float4*)(sig + k0);
                float4 x1 = *(const float4*)(sig + k0 + 4);
                s += x0.x + x0.y + x0.z + x0.w + x1.x + x1.y + x1.z + x1.w;
            }
        }
        s += __shfl_xor(s, 1);
        s += __shfl_xor(s, 2);
        s += __shfl_xor(s, 4);
        float mean = s * (1.0f / (float)KLEN);

        #pragma unroll
        for (int i = 0; i < 7; ++i) {
            int k0 = og * 8 + 64 * i;
            if (k0 < KA) {
                f16x8 hv, lv;
                if (k0 < KLEN) {
                    float4 x0 = *(const float4*)(sig + k0);
                    float4 x1 = *(const float4*)(sig + k0 + 4);
                    float4 w0 = *(const float4*)(window + k0);
                    float4 w1 = *(const float4*)(window + k0 + 4);
                    float xm1 = (k0 > 0) ? sig[k0 - 1] : x0.x;
                    float xs[8] = {x0.x, x0.y, x0.z, x0.w, x1.x, x1.y, x1.z, x1.w};
                    float wv[8] = {w0.x, w0.y, w0.z, w0.w, w1.x, w1.y, w1.z, w1.w};
                    #pragma unroll
                    for (int j = 0; j < 8; ++j) {
                        float xp = (j == 0) ? xm1 : xs[j - 1];
                        float y  = (xs[j] - 0.97f * xp - 0.03f * mean) * wv[j];
                        _Float16 h = (_Float16)y;
                        hv[j] = h;
                        lv[j] = (_Float16)((y - (float)h) * SPLIT_S);
                    }
                } else {
                    #pragma unroll
                    for (int j = 0; j < 8; ++j) { hv[j] = (_Float16)0.f; lv[j] = (_Float16)0.f; }
                }
                *(f16x8*)&Ah[fr][k0] = hv;
                *(f16x8*)&Al[fr][k0] = lv;
            }
        }
    }
    __syncthreads();                        // A planes ready

    const int wn = wid;                     // wave -> 32-col strip
    const int q  = lane >> 4, lr = lane & 15;
    const int mf = tid & 31;                // mel: frame
    const int mg = tid >> 5;                // mel: 0..7 (mels mg, mg+8, ..., mg+72)

    int lo10[10], hi10[10];
    #pragma unroll
    for (int t = 0; t < 10; ++t) { lo10[t] = mlo[mg + 8 * t]; hi10[t] = mhi[mg + 8 * t]; }

    float accm[10];
    #pragma unroll
    for (int t = 0; t < 10; ++t) accm[t] = 0.f;

    for (int n0 = 0; n0 < 512; n0 += 128) {
        f32x4 aM[2][2], aC[2][2];
        #pragma unroll
        for (int mt = 0; mt < 2; ++mt)
            #pragma unroll
            for (int nt = 0; nt < 2; ++nt) {
                aM[mt][nt] = (f32x4){0.f, 0.f, 0.f, 0.f};
                aC[mt][nt] = (f32x4){0.f, 0.f, 0.f, 0.f};
            }

        // per-lane pre-split B fragment pointers (col n, k-chunk q)
        const _Float16* bhp[2];
        const _Float16* blp[2];
        #pragma unroll
        for (int nt = 0; nt < 2; ++nt) {
            int n = n0 + wn * 32 + nt * 16 + lr;
            size_t off = (size_t)n * KA + q * 8;
            bhp[nt] = Bh + off;
            blp[nt] = Bl + off;
        }

        // ---- software-pipelined K loop: A dbuf (depth 1), B tbuf (depth 2) ----
        f16x8 ah[2][2], al[2][2];           // [buf][mt]
        f16x8 bh[3][2], bl[3][2];           // [buf][nt]

        #pragma unroll
        for (int mt = 0; mt < 2; ++mt) {
            ah[0][mt] = *(const f16x8*)&Ah[mt * 16 + lr][q * 8];
            al[0][mt] = *(const f16x8*)&Al[mt * 16 + lr][q * 8];
        }
        #pragma unroll
        for (int nt = 0; nt < 2; ++nt) {
            bh[0][nt] = *(const f16x8*)(bhp[nt]);
            bl[0][nt] = *(const f16x8*)(blp[nt]);
            bh[1][nt] = *(const f16x8*)(bhp[nt] + 32);
            bl[1][nt] = *(const f16x8*)(blp[nt] + 32);
        }

        #pragma unroll
        for (int s = 0; s < 13; ++s) {
            const int kk = s * 32;
            if (s + 1 < 13) {               // A prefetch (LDS)
                #pragma unroll
                for (int mt = 0; mt < 2; ++mt) {
                    ah[(s + 1) & 1][mt] = *(const f16x8*)&Ah[mt * 16 + lr][kk + 32 + q * 8];
                    al[(s + 1) & 1][mt] = *(const f16x8*)&Al[mt * 16 + lr][kk + 32 + q * 8];
                }
            }
            if (s + 2 < 13) {               // B prefetch (global, depth 2)
                #pragma unroll
                for (int nt = 0; nt < 2; ++nt) {
                    bh[(s + 2) % 3][nt] = *(const f16x8*)(bhp[nt] + kk + 64);
                    bl[(s + 2) % 3][nt] = *(const f16x8*)(blp[nt] + kk + 64);
                }
            }
            const int ab = s & 1, bb = s % 3;
            #pragma unroll
            for (int mt = 0; mt < 2; ++mt)
                #pragma unroll
                for (int nt = 0; nt < 2; ++nt)
                    aM[mt][nt] = __builtin_amdgcn_mfma_f32_16x16x32_f16(
                        ah[ab][mt], bh[bb][nt], aM[mt][nt], 0, 0, 0);
            #pragma unroll
            for (int mt = 0; mt < 2; ++mt)
                #pragma unroll
                for (int nt = 0; nt < 2; ++nt)
                    aC[mt][nt] = __builtin_amdgcn_mfma_f32_16x16x32_f16(
                        al[ab][mt], bh[bb][nt], aC[mt][nt], 0, 0, 0);
            #pragma unroll
            for (int mt = 0; mt < 2; ++mt)
                #pragma unroll
                for (int nt = 0; nt < 2; ++nt)
                    aC[mt][nt] = __builtin_amdgcn_mfma_f32_16x16x32_f16(
                        ah[ab][mt], bl[bb][nt], aC[mt][nt], 0, 0, 0);
        }

        // ---- spectrum epilogue: combine split planes, pair re/im via shfl ----
        __syncthreads();                    // prior pass's mel Sp-reads done
        #pragma unroll
        for (int mt = 0; mt < 2; ++mt)
            #pragma unroll
            for (int nt = 0; nt < 2; ++nt)
                #pragma unroll
                for (int r = 0; r < 4; ++r) {
                    float v = aM[mt][nt][r] + aC[mt][nt][r] * SPLIT_INV;
                    float o = __shfl_xor(v, 1);
                    if ((lane & 1) == 0) {
                        int row = mt * 16 + q * 4 + r;               // frame 0..31
                        int bin = (wn * 32 + nt * 16 + lr) >> 1;     // 0..63
                        Sp[row][bin] = v * v + o * o;
                    }
                }
        __syncthreads();                    // Sp visible

        // ---- sparse mel, vectorized: melfT is 0 outside [lo,hi) so aligned
        // float4 over-reads are numerically exact (0 * Sp). k4 stays within
        // [kb0, kb0+60] -> Sp index <= 63; melfT tail 257..259 zeroed in k_prep.
        int kb0 = n0 >> 1;
        #pragma unroll
        for (int t = 0; t < 10; ++t) {
            int ks = lo10[t] > kb0 ? lo10[t] : kb0;
            int ke = hi10[t] < kb0 + 64 ? hi10[t] : kb0 + 64;
            const float* wrow = melfT + (size_t)(mg + 8 * t) * MTS;
            for (int k4 = ks & ~3; k4 < ke; k4 += 4) {
                f32x4  sv = *(const f32x4*)&Sp[mf][k4 - kb0];
                float4 wv = *(const float4*)(wrow + k4);
                accm[t] += sv[0] * wv.x + sv[1] * wv.y + sv[2] * wv.z + sv[3] * wv.w;
            }
        }
    }

    // ---- re-apply 32768^2, log, fp32 store ----
    {
        size_t row = (size_t)tile * 32 + mf;
        #pragma unroll
        for (int t = 0; t < 10; ++t)
            out[row * NMEL + mg + 8 * t] = logf(fmaxf(accm[t] * SCALE2, EPS_F));
    }
}

// ---------------- kernel 2 (fallback): in-register B split (round-1 kernel) ---
__global__ __launch_bounds__(256) void k_main(const float* __restrict__ wav,
                                              const float* __restrict__ window,
                                              const float* __restrict__ melfT,
                                              const int* __restrict__ mlo,
                                              const int* __restrict__ mhi,
                                              const float* __restrict__ dcos,
                                              const float* __restrict__ dsin,
                                              float* __restrict__ out)
{
    __shared__ __align__(16) _Float16 Ah[32][424];
    __shared__ __align__(16) _Float16 Al[32][424];
    __shared__ __align__(16) float    Sp[32][66];

    const int tid  = threadIdx.x;
    const int lane = tid & 63;
    const int wid  = tid >> 6;
    const int tile = blockIdx.x;

    {
        int fr = tid >> 3, og = tid & 7;
        int fb = tile * 32 + fr;
        int b  = fb / NFRAMES;
        int f  = fb - b * NFRAMES;
        const float* sig = wav + (size_t)b * T_SAMP + (size_t)f * 160;

        float s = 0.f;
        #pragma unroll
        for (int i = 0; i < 7; ++i) {
            int k0 = og * 8 + 64 * i;
            if (k0 < KLEN) {
                float4 x0 = *(const float4*)(sig + k0);
                float4 x1 = *(const float4*)(sig + k0 + 4);
                s += x0.x + x0.y + x0.z + x0.w + x1.x + x1.y + x1.z + x1.w;
            }
        }
        s += __shfl_xor(s, 1);
        s += __shfl_xor(s, 2);
        s += __shfl_xor(s, 4);
        float mean = s * (1.0f / (float)KLEN);

        #pragma unroll
        for (int i = 0; i < 7; ++i) {
            int k0 = og * 8 + 64 * i;
            if (k0 < KA) {
                f16x8 hv, lv;
                if (k0 < KLEN) {
                    float4 x0 = *(const float4*)(sig + k0);
                    float4 x1 = *(const float4*)(sig + k0 + 4);
                    float4 w0 = *(const float4*)(window + k0);
                    float4 w1 = *(const float4*)(window + k0 + 4);
                    float xm1 = (k0 > 0) ? sig[k0 - 1] : x0.x;
                    float xs[8] = {x0.x, x0.y, x0.z, x0.w, x1.x, x1.y, x1.z, x1.w};
                    float wv[8] = {w0.x, w0.y, w0.z, w0.w, w1.x, w1.y, w1.z, w1.w};
                    #pragma unroll
                    for (int j = 0; j < 8; ++j) {
                        float xp = (j == 0) ? xm1 : xs[j - 1];
                        float y  = (xs[j] - 0.97f * xp - 0.03f * mean) * wv[j];
                        _Float16 h = (_Float16)y;
                        hv[j] = h;
                        lv[j] = (_Float16)((y - (float)h) * SPLIT_S);
                    }
                } else {
                    #pragma unroll
                    for (int j = 0; j < 8; ++j) { hv[j] = (_Float16)0.f; lv[j] = (_Float16)0.f; }
                }
                *(f16x8*)&Ah[fr][k0] = hv;
                *(f16x8*)&Al[fr][k0] = lv;
            }
        }
    }
    __syncthreads();

    const int wn = wid;
    const int q  = lane >> 4, lr = lane & 15;
    const int mf = tid & 31;
    const int mg = tid >> 5;

    int lo10[10], hi10[10];
    #pragma unroll
    for (int t = 0; t < 10; ++t) { lo10[t] = mlo[mg + 8 * t]; hi10[t] = mhi[mg + 8 * t]; }

    float accm[10];
    #pragma unroll
    for (int t = 0; t < 10; ++t) accm[t] = 0.f;

    for (int n0 = 0; n0 < 512; n0 += 128) {
        f32x4 aM[2][2], aX[2][2], aY[2][2];
        #pragma unroll
        for (int mt = 0; mt < 2; ++mt)
            #pragma unroll
            for (int nt = 0; nt < 2; ++nt) {
                aM[mt][nt] = (f32x4){0.f, 0.f, 0.f, 0.f};
                aX[mt][nt] = (f32x4){0.f, 0.f, 0.f, 0.f};
                aY[mt][nt] = (f32x4){0.f, 0.f, 0.f, 0.f};
            }

        const float* bp[2];
        #pragma unroll
        for (int nt = 0; nt < 2; ++nt) {
            int n = n0 + wn * 32 + nt * 16 + lr;
            bp[nt] = ((n & 1) ? dsin : dcos) + (size_t)(n >> 1) * 512 + q * 8;
        }

        for (int kk = 0; kk < KA; kk += 32) {
            f16x8 ah[2], al[2], bh[2], bl[2];
            #pragma unroll
            for (int mt = 0; mt < 2; ++mt) {
                ah[mt] = *(const f16x8*)&Ah[mt * 16 + lr][kk + q * 8];
                al[mt] = *(const f16x8*)&Al[mt * 16 + lr][kk + q * 8];
            }
            #pragma unroll
            for (int nt = 0; nt < 2; ++nt) {
                float4 b0 = *(const float4*)(bp[nt] + kk);
                float4 b1 = *(const float4*)(bp[nt] + kk + 4);
                float bv[8] = {b0.x, b0.y, b0.z, b0.w, b1.x, b1.y, b1.z, b1.w};
                #pragma unroll
                for (int j = 0; j < 8; ++j) {
                    _Float16 h = (_Float16)bv[j];
                    bh[nt][j] = h;
                    bl[nt][j] = (_Float16)((bv[j] - (float)h) * SPLIT_S);
                }
            }
            #pragma unroll
            for (int mt = 0; mt < 2; ++mt)
                #pragma unroll
                for (int nt = 0; nt < 2; ++nt) {
                    aM[mt][nt] = __builtin_amdgcn_mfma_f32_16x16x32_f16(
                        ah[mt], bh[nt], aM[mt][nt], 0, 0, 0);
                    aX[mt][nt] = __builtin_amdgcn_mfma_f32_16x16x32_f16(
                        ah[mt], bl[nt], aX[mt][nt], 0, 0, 0);
                    aY[mt][nt] = __builtin_amdgcn_mfma_f32_16x16x32_f16(
                        al[mt], bh[nt], aY[mt][nt], 0, 0, 0);
                }
        }

        __syncthreads();
        #pragma unroll
        for (int mt = 0; mt < 2; ++mt)
            #pragma unroll
            for (int nt = 0; nt < 2; ++nt)
                #pragma unroll
                for (int r = 0; r < 4; ++r) {
                    float v = aM[mt][nt][r]
                            + (aX[mt][nt][r] + aY[mt][nt][r]) * SPLIT_INV;
                    float o = __shfl_xor(v, 1);
                    if ((lane & 1) == 0) {
                        int row = mt * 16 + q * 4 + r;
                        int bin = (wn * 32 + nt * 16 + lr) >> 1;
                        Sp[row][bin] = v * v + o * o;
                    }
                }
        __syncthreads();

        int kb0 = n0 >> 1;
        #pragma unroll
        for (int t = 0; t < 10; ++t) {
            int ks = lo10[t] > kb0 ? lo10[t] : kb0;
            int ke = hi10[t] < kb0 + 64 ? hi10[t] : kb0 + 64;
            const float* wrow = melfT + (size_t)(mg + 8 * t) * MTS;
            for (int k = ks; k < ke; ++k)
                accm[t] += Sp[mf][k - kb0] * wrow[k];
        }
    }

    {
        size_t row = (size_t)tile * 32 + mf;
        #pragma unroll
        for (int t = 0; t < 10; ++t)
            out[row * NMEL + mg + 8 * t] = logf(fmaxf(accm[t] * SCALE2, EPS_F));
    }
}

// ---------------- kernel 3: per-(batch,mel) sums over frames (fp32) ----------
__global__ __launch_bounds__(256) void k_mean(const float* __restrict__ out,
                                              float* __restrict__ means)
{
    __shared__ float red[240];
    int b = blockIdx.y, tid = threadIdx.x;
    int f0   = blockIdx.x * 375;
    int fend = min(f0 + 375, NFRAMES);
    int r = tid / 80, m = tid - r * 80;
    if (tid < 240) {
        float s = 0.f;
        const float* base = out + (size_t)b * NFRAMES * NMEL;
        for (int f = f0 + r; f < fend; f += 3)
            s += base[(size_t)f * NMEL + m];
        red[tid] = s;
    }
    __syncthreads();
    if (tid < 80)
        atomicAdd(&means[b * NMEL + tid], red[tid] + red[tid + 80] + red[tid + 160]);
}

// ---------------- kernel 4: subtract mean in-place (fp32) ----------
__global__ __launch_bounds__(256) void k_norm(const float* __restrict__ means,
                                              float* __restrict__ out)
{
    const int PER = NFRAMES * NMEL;           // 239,840
    int b = blockIdx.y;
    int e = blockIdx.x * 256 + threadIdx.x;
    if (e < PER) {
        int m = e % NMEL;
        size_t idx = (size_t)b * PER + e;
        out[idx] = out[idx] - means[b * NMEL + m] * (1.0f / (float)NFRAMES);
    }
}

// ---------------- launch ----------------
extern "C" void kernel_launch(void* const* d_in, const int* in_sizes, int n_in,
                              void* d_out, int out_size, void* d_ws, size_t ws_size,
                              hipStream_t stream)
{
    const float* wav    = (const float*)d_in[0];
    const float* window = (const float*)d_in[1];
    const float* melf   = (const float*)d_in[2];
    const float* dcos   = (const float*)d_in[3];
    const float* dsin   = (const float*)d_in[4];
    float* out = (float*)d_out;

    // ws layout:
    //   means fp32 32*80   @ 0        (10,240)
    //   mlo   int  80      @ 10,240   (320)
    //   mhi   int  80      @ 10,560   (320)
    //   melfT fp32 80*260  @ 10,880   (83,200)   -> 94,080
    //   Bh    f16  512*416 @ 94,208   (425,984)  -> 520,192   [fast path only]
    //   Bl    f16  512*416 @ 520,192  (425,984)  -> 946,176
    char* ws = (char*)d_ws;
    float*     means = (float*)ws;
    int*       mlo   = (int*)(ws + 10240);
    int*       mhi   = (int*)(ws + 10560);
    float*     melfT = (float*)(ws + 10880);
    _Float16*  Bh    = (_Float16*)(ws + 94208);
    _Float16*  Bl    = (_Float16*)(ws + 520192);

    const int pre = (ws_size >= 946176) ? 1 : 0;

    FbankWrapper_14285061226526_kernel<<<10, 256, 0, stream>>>(means);
    k_prep<<<184, 256, 0, stream>>>(melf, dcos, dsin, mlo, mhi, melfT, Bh, Bl, pre);
    if (pre) {
        k_main_pre<<<2998, 256, 0, stream>>>(wav, window, melfT, mlo, mhi, Bh, Bl, out);
    } else {
        k_main<<<2998, 256, 0, stream>>>(wav, window, melfT, mlo, mhi, dcos, dsin, out);
    }
    k_mean<<<dim3(8, BATCH), 256, 0, stream>>>(out, means);
    k_norm<<<dim3((NFRAMES * NMEL + 255) / 256, BATCH), 256, 0, stream>>>(means, out);
}

// Round 4
// 351.467 us; speedup vs baseline: 1.4674x; 1.0349x over previous
//
#include <hip/hip_runtime.h>

// ---------------- problem constants ----------------
#define BATCH     32
#define T_SAMP    480000
#define NFRAMES   2998
#define KLEN      400
#define KA        416             // 13*32 ; k 400..415 zero-padded
#define NMEL      80
#define EPS_F     1.1920928955078125e-07f
#define SCALE2    1073741824.0f   // 32768^2, re-applied before log (A unscaled)
#define SPLIT_S   2048.0f         // lo-plane scale (keeps lo in fp16 normal range)
#define SPLIT_INV 4.8828125e-4f   // 1/2048
#define MTS       260             // melfT row stride (floats)

typedef _Float16 f16x8 __attribute__((ext_vector_type(8)));
typedef float    f32x4 __attribute__((ext_vector_type(4)));

// ---------------- kernel 0: zero the means accumulator (name kept for harness) --
__global__ __launch_bounds__(256) void FbankWrapper_14285061226526_kernel(float* means)
{
    int i = blockIdx.x * 256 + threadIdx.x;
    if (i < BATCH * NMEL) means[i] = 0.f;
}

// ---------------- kernel 1: fused setup ----------------------------------------
// blocks 0..79   : melfT row m = transpose of melf col m + per-mel lo/hi ranges
// blocks 80..183 : pre-split DFT basis into fp16 hi/lo planes, K-CHUNKED layout:
//                  elem (n,k) at ((k>>3)*512 + n)*8 + (k&7)  [n = re/im-interleaved
//                  col, k = sample index 0..415]. Makes k_main's B loads coalesced:
//                  adjacent lanes (n,n+1) are 16 B apart instead of 832 B.
__global__ __launch_bounds__(256) void k_prep(const float* __restrict__ melf,
                                              const float* __restrict__ dcos,
                                              const float* __restrict__ dsin,
                                              int* __restrict__ mlo,
                                              int* __restrict__ mhi,
                                              float* __restrict__ melfT,
                                              _Float16* __restrict__ Bh,
                                              _Float16* __restrict__ Bl,
                                              int pre)
{
    const int bid = blockIdx.x;
    const int tid = threadIdx.x;

    if (bid < 80) {
        __shared__ int slo, shi;
        if (tid == 0) { slo = 256; shi = 0; }
        __syncthreads();
        const int m = bid;
        float w = melf[(size_t)tid * NMEL + m];
        melfT[(size_t)m * MTS + tid] = w;
        int lom = (w > 0.f) ? tid : 256;
        int him = (w > 0.f) ? tid + 1 : 0;
        if (tid == 0) {
            float w2 = melf[(size_t)256 * NMEL + m];
            melfT[(size_t)m * MTS + 256] = w2;
            if (w2 > 0.f) { lom = 256 < lom ? 256 : lom; him = 257; }
            melfT[(size_t)m * MTS + 257] = 0.f;
            melfT[(size_t)m * MTS + 258] = 0.f;
            melfT[(size_t)m * MTS + 259] = 0.f;
        }
        atomicMin(&slo, lom);
        atomicMax(&shi, him);
        __syncthreads();
        if (tid == 0) { mlo[m] = slo; mhi[m] = shi; }
        return;
    }

    if (!pre) return;
    int id = (bid - 80) * 256 + tid;          // 0..26623 = 52 chunks * 512 cols
    if (id >= 52 * 512) return;
    int c = id >> 9;                          // k-chunk 0..51
    int n = id & 511;                         // col
    int k = c * 8;
    const float* src = ((n & 1) ? dsin : dcos) + (size_t)(n >> 1) * 512 + k;
    f16x8 hv, lv;
    #pragma unroll
    for (int j = 0; j < 8; ++j) {
        float v = src[j];
        _Float16 h = (_Float16)v;
        hv[j] = h;
        lv[j] = (_Float16)((v - (float)h) * SPLIT_S);
    }
    *(f16x8*)(Bh + (size_t)id * 8) = hv;      // ((c*512)+n)*8
    *(f16x8*)(Bl + (size_t)id * 8) = lv;
}

// ---------------- kernel 2 (fast path): pipelined split-fp16 MFMA DFT ----------
// one block = 32 frames. A planes LDS-resident; B planes pre-split + k-chunked
// in workspace (coalesced 16-line loads). K-loop unrolled (13 steps): B regs
// triple-buffered (depth-2 prefetch), A regs double-buffered.
// C = Ah*Bh + (Al*Bh + Ah*Bl)/2048, merged correction accumulator.
// __launch_bounds__(256,2): LDS caps at 2 blocks/CU anyway -> free the VGPR
// budget (up to 256) so the compiler can keep the pipeline in registers.
__global__ __launch_bounds__(256, 2) void k_main_pre(const float* __restrict__ wav,
                                                     const float* __restrict__ window,
                                                     const float* __restrict__ melfT,
                                                     const int* __restrict__ mlo,
                                                     const int* __restrict__ mhi,
                                                     const _Float16* __restrict__ Bh,
                                                     const _Float16* __restrict__ Bl,
                                                     float* __restrict__ out)
{
    __shared__ __align__(16) _Float16 Ah[32][424];   // 27,136 B
    __shared__ __align__(16) _Float16 Al[32][424];   // 27,136 B
    __shared__ __align__(16) float    Sp[32][68];    //  8,704 B  (62,976 total)

    const int tid  = threadIdx.x;
    const int lane = tid & 63;
    const int wid  = tid >> 6;
    const int tile = blockIdx.x;            // 0..2997

    // ---- prep: 8 threads per frame; mean via 8-lane shuffle; split to hi/lo ----
    {
        int fr = tid >> 3, og = tid & 7;
        int fb = tile * 32 + fr;
        int b  = fb / NFRAMES;
        int f  = fb - b * NFRAMES;
        const float* sig = wav + (size_t)b * T_SAMP + (size_t)f * 160;

        float s = 0.f;
        #pragma unroll
        for (int i = 0; i < 7; ++i) {
            int k0 = og * 8 + 64 * i;
            if (k0 < KLEN) {
                float4 x0 = *(const float4*)(sig + k0);
                float4 x1 = *(const float4*)(sig + k0 + 4);
                s += x0.x + x0.y + x0.z + x0.w + x1.x + x1.y + x1.z + x1.w;
            }
        }
        s += __shfl_xor(s, 1);
        s += __shfl_xor(s, 2);
        s += __shfl_xor(s, 4);
        float mean = s * (1.0f / (float)KLEN);

        #pragma unroll
        for (int i = 0; i < 7; ++i) {
            int k0 = og * 8 + 64 * i;
            if (k0 < KA) {
                f16x8 hv, lv;
                if (k0 < KLEN) {
                    float4 x0 = *(const float4*)(sig + k0);
                    float4 x1 = *(const float4*)(sig + k0 + 4);
                    float4 w0 = *(const float4*)(window + k0);
                    float4 w1 = *(const float4*)(window + k0 + 4);
                    float xm1 = (k0 > 0) ? sig[k0 - 1] : x0.x;
                    float xs[8] = {x0.x, x0.y, x0.z, x0.w, x1.x, x1.y, x1.z, x1.w};
                    float wv[8] = {w0.x, w0.y, w0.z, w0.w, w1.x, w1.y, w1.z, w1.w};
                    #pragma unroll
                    for (int j = 0; j < 8; ++j) {
                        float xp = (j == 0) ? xm1 : xs[j - 1];
                        float y  = (xs[j] - 0.97f * xp - 0.03f * mean) * wv[j];
                        _Float16 h = (_Float16)y;
                        hv[j] = h;
                        lv[j] = (_Float16)((y - (float)h) * SPLIT_S);
                    }
                } else {
                    #pragma unroll
                    for (int j = 0; j < 8; ++j) { hv[j] = (_Float16)0.f; lv[j] = (_Float16)0.f; }
                }
                *(f16x8*)&Ah[fr][k0] = hv;
                *(f16x8*)&Al[fr][k0] = lv;
            }
        }
    }
    __syncthreads();                        // A planes ready

    const int wn = wid;                     // wave -> 32-col strip
    const int q  = lane >> 4, lr = lane & 15;
    const int mf = tid & 31;                // mel: frame
    const int mg = tid >> 5;                // mel: 0..7 (mels mg, mg+8, ..., mg+72)

    int lo10[10], hi10[10];
    #pragma unroll
    for (int t = 0; t < 10; ++t) { lo10[t] = mlo[mg + 8 * t]; hi10[t] = mhi[mg + 8 * t]; }

    float accm[10];
    #pragma unroll
    for (int t = 0; t < 10; ++t) accm[t] = 0.f;

    for (int n0 = 0; n0 < 512; n0 += 128) {
        f32x4 aM[2][2], aC[2][2];
        #pragma unroll
        for (int mt = 0; mt < 2; ++mt)
            #pragma unroll
            for (int nt = 0; nt < 2; ++nt) {
                aM[mt][nt] = (f32x4){0.f, 0.f, 0.f, 0.f};
                aC[mt][nt] = (f32x4){0.f, 0.f, 0.f, 0.f};
            }

        // per-lane B base in k-chunked layout: (n,k) -> ((k>>3)*512 + n)*8 + (k&7).
        // lane covers k = kk + q*8 .. +8  ->  offset (kk/8 + q)*4096 + n*8.
        // per k-step (32 k) advance = 4 chunks * 4096 = 16384 f16.
        const _Float16* bph[2];
        const _Float16* blp[2];
        #pragma unroll
        for (int nt = 0; nt < 2; ++nt) {
            int n = n0 + wn * 32 + nt * 16 + lr;
            size_t off = (size_t)q * 4096 + (size_t)n * 8;
            bph[nt] = Bh + off;
            blp[nt] = Bl + off;
        }

        // ---- software-pipelined K loop: A dbuf (depth 1), B tbuf (depth 2) ----
        f16x8 ah[2][2], al[2][2];           // [buf][mt]
        f16x8 bh[3][2], bl[3][2];           // [buf][nt]

        #pragma unroll
        for (int mt = 0; mt < 2; ++mt) {
            ah[0][mt] = *(const f16x8*)&Ah[mt * 16 + lr][q * 8];
            al[0][mt] = *(const f16x8*)&Al[mt * 16 + lr][q * 8];
        }
        #pragma unroll
        for (int nt = 0; nt < 2; ++nt) {
            bh[0][nt] = *(const f16x8*)(bph[nt]);
            bl[0][nt] = *(const f16x8*)(blp[nt]);
            bh[1][nt] = *(const f16x8*)(bph[nt] + 16384);
            bl[1][nt] = *(const f16x8*)(blp[nt] + 16384);
        }

        #pragma unroll
        for (int s = 0; s < 13; ++s) {
            const int kk = s * 32;
            if (s + 1 < 13) {               // A prefetch (LDS)
                #pragma unroll
                for (int mt = 0; mt < 2; ++mt) {
                    ah[(s + 1) & 1][mt] = *(const f16x8*)&Ah[mt * 16 + lr][kk + 32 + q * 8];
                    al[(s + 1) & 1][mt] = *(const f16x8*)&Al[mt * 16 + lr][kk + 32 + q * 8];
                }
            }
            if (s + 2 < 13) {               // B prefetch (global, depth 2, coalesced)
                #pragma unroll
                for (int nt = 0; nt < 2; ++nt) {
                    bh[(s + 2) % 3][nt] = *(const f16x8*)(bph[nt] + (size_t)(s + 2) * 16384);
                    bl[(s + 2) % 3][nt] = *(const f16x8*)(blp[nt] + (size_t)(s + 2) * 16384);
                }
            }
            const int ab = s & 1, bb = s % 3;
            #pragma unroll
            for (int mt = 0; mt < 2; ++mt)
                #pragma unroll
                for (int nt = 0; nt < 2; ++nt)
                    aM[mt][nt] = __builtin_amdgcn_mfma_f32_16x16x32_f16(
                        ah[ab][mt], bh[bb][nt], aM[mt][nt], 0, 0, 0);
            #pragma unroll
            for (int mt = 0; mt < 2; ++mt)
                #pragma unroll
                for (int nt = 0; nt < 2; ++nt)
                    aC[mt][nt] = __builtin_amdgcn_mfma_f32_16x16x32_f16(
                        al[ab][mt], bh[bb][nt], aC[mt][nt], 0, 0, 0);
            #pragma unroll
            for (int mt = 0; mt < 2; ++mt)
                #pragma unroll
                for (int nt = 0; nt < 2; ++nt)
                    aC[mt][nt] = __builtin_amdgcn_mfma_f32_16x16x32_f16(
                        ah[ab][mt], bl[bb][nt], aC[mt][nt], 0, 0, 0);
        }

        // ---- spectrum epilogue: combine split planes, pair re/im via shfl ----
        __syncthreads();                    // prior pass's mel Sp-reads done
        #pragma unroll
        for (int mt = 0; mt < 2; ++mt)
            #pragma unroll
            for (int nt = 0; nt < 2; ++nt)
                #pragma unroll
                for (int r = 0; r < 4; ++r) {
                    float v = aM[mt][nt][r] + aC[mt][nt][r] * SPLIT_INV;
                    float o = __shfl_xor(v, 1);
                    if ((lane & 1) == 0) {
                        int row = mt * 16 + q * 4 + r;               // frame 0..31
                        int bin = (wn * 32 + nt * 16 + lr) >> 1;     // 0..63
                        Sp[row][bin] = v * v + o * o;
                    }
                }
        __syncthreads();                    // Sp visible

        // ---- sparse mel, vectorized: melfT is 0 outside [lo,hi) so aligned
        // float4 over-reads are numerically exact. Sp idx <= 63; melfT tail
        // 257..259 zeroed in k_prep.
        int kb0 = n0 >> 1;
        #pragma unroll
        for (int t = 0; t < 10; ++t) {
            int ks = lo10[t] > kb0 ? lo10[t] : kb0;
            int ke = hi10[t] < kb0 + 64 ? hi10[t] : kb0 + 64;
            const float* wrow = melfT + (size_t)(mg + 8 * t) * MTS;
            for (int k4 = ks & ~3; k4 < ke; k4 += 4) {
                f32x4  sv = *(const f32x4*)&Sp[mf][k4 - kb0];
                float4 wv = *(const float4*)(wrow + k4);
                accm[t] += sv[0] * wv.x + sv[1] * wv.y + sv[2] * wv.z + sv[3] * wv.w;
            }
        }
    }

    // ---- re-apply 32768^2, log, fp32 store ----
    {
        size_t row = (size_t)tile * 32 + mf;
        #pragma unroll
        for (int t = 0; t < 10; ++t)
            out[row * NMEL + mg + 8 * t] = logf(fmaxf(accm[t] * SCALE2, EPS_F));
    }
}

// ---------------- kernel 2 (fallback): in-register B split (round-1 kernel) ---
__global__ __launch_bounds__(256) void k_main(const float* __restrict__ wav,
                                              const float* __restrict__ window,
                                              const float* __restrict__ melfT,
                                              const int* __restrict__ mlo,
                                              const int* __restrict__ mhi,
                                              const float* __restrict__ dcos,
                                              const float* __restrict__ dsin,
                                              float* __restrict__ out)
{
    __shared__ __align__(16) _Float16 Ah[32][424];
    __shared__ __align__(16) _Float16 Al[32][424];
    __shared__ __align__(16) float    Sp[32][66];

    const int tid  = threadIdx.x;
    const int lane = tid & 63;
    const int wid  = tid >> 6;
    const int tile = blockIdx.x;

    {
        int fr = tid >> 3, og = tid & 7;
        int fb = tile * 32 + fr;
        int b  = fb / NFRAMES;
        int f  = fb - b * NFRAMES;
        const float* sig = wav + (size_t)b * T_SAMP + (size_t)f * 160;

        float s = 0.f;
        #pragma unroll
        for (int i = 0; i < 7; ++i) {
            int k0 = og * 8 + 64 * i;
            if (k0 < KLEN) {
                float4 x0 = *(const float4*)(sig + k0);
                float4 x1 = *(const float4*)(sig + k0 + 4);
                s += x0.x + x0.y + x0.z + x0.w + x1.x + x1.y + x1.z + x1.w;
            }
        }
        s += __shfl_xor(s, 1);
        s += __shfl_xor(s, 2);
        s += __shfl_xor(s, 4);
        float mean = s * (1.0f / (float)KLEN);

        #pragma unroll
        for (int i = 0; i < 7; ++i) {
            int k0 = og * 8 + 64 * i;
            if (k0 < KA) {
                f16x8 hv, lv;
                if (k0 < KLEN) {
                    float4 x0 = *(const float4*)(sig + k0);
                    float4 x1 = *(const float4*)(sig + k0 + 4);
                    float4 w0 = *(const float4*)(window + k0);
                    float4 w1 = *(const float4*)(window + k0 + 4);
                    float xm1 = (k0 > 0) ? sig[k0 - 1] : x0.x;
                    float xs[8] = {x0.x, x0.y, x0.z, x0.w, x1.x, x1.y, x1.z, x1.w};
                    float wv[8] = {w0.x, w0.y, w0.z, w0.w, w1.x, w1.y, w1.z, w1.w};
                    #pragma unroll
                    for (int j = 0; j < 8; ++j) {
                        float xp = (j == 0) ? xm1 : xs[j - 1];
                        float y  = (xs[j] - 0.97f * xp - 0.03f * mean) * wv[j];
                        _Float16 h = (_Float16)y;
                        hv[j] = h;
                        lv[j] = (_Float16)((y - (float)h) * SPLIT_S);
                    }
                } else {
                    #pragma unroll
                    for (int j = 0; j < 8; ++j) { hv[j] = (_Float16)0.f; lv[j] = (_Float16)0.f; }
                }
                *(f16x8*)&Ah[fr][k0] = hv;
                *(f16x8*)&Al[fr][k0] = lv;
            }
        }
    }
    __syncthreads();

    const int wn = wid;
    const int q  = lane >> 4, lr = lane & 15;
    const int mf = tid & 31;
    const int mg = tid >> 5;

    int lo10[10], hi10[10];
    #pragma unroll
    for (int t = 0; t < 10; ++t) { lo10[t] = mlo[mg + 8 * t]; hi10[t] = mhi[mg + 8 * t]; }

    float accm[10];
    #pragma unroll
    for (int t = 0; t < 10; ++t) accm[t] = 0.f;

    for (int n0 = 0; n0 < 512; n0 += 128) {
        f32x4 aM[2][2], aX[2][2], aY[2][2];
        #pragma unroll
        for (int mt = 0; mt < 2; ++mt)
            #pragma unroll
            for (int nt = 0; nt < 2; ++nt) {
                aM[mt][nt] = (f32x4){0.f, 0.f, 0.f, 0.f};
                aX[mt][nt] = (f32x4){0.f, 0.f, 0.f, 0.f};
                aY[mt][nt] = (f32x4){0.f, 0.f, 0.f, 0.f};
            }

        const float* bp[2];
        #pragma unroll
        for (int nt = 0; nt < 2; ++nt) {
            int n = n0 + wn * 32 + nt * 16 + lr;
            bp[nt] = ((n & 1) ? dsin : dcos) + (size_t)(n >> 1) * 512 + q * 8;
        }

        for (int kk = 0; kk < KA; kk += 32) {
            f16x8 ah[2], al[2], bh[2], bl[2];
            #pragma unroll
            for (int mt = 0; mt < 2; ++mt) {
                ah[mt] = *(const f16x8*)&Ah[mt * 16 + lr][kk + q * 8];
                al[mt] = *(const f16x8*)&Al[mt * 16 + lr][kk + q * 8];
            }
            #pragma unroll
            for (int nt = 0; nt < 2; ++nt) {
                float4 b0 = *(const float4*)(bp[nt] + kk);
                float4 b1 = *(const float4*)(bp[nt] + kk + 4);
                float bv[8] = {b0.x, b0.y, b0.z, b0.w, b1.x, b1.y, b1.z, b1.w};
                #pragma unroll
                for (int j = 0; j < 8; ++j) {
                    _Float16 h = (_Float16)bv[j];
                    bh[nt][j] = h;
                    bl[nt][j] = (_Float16)((bv[j] - (float)h) * SPLIT_S);
                }
            }
            #pragma unroll
            for (int mt = 0; mt < 2; ++mt)
                #pragma unroll
                for (int nt = 0; nt < 2; ++nt) {
                    aM[mt][nt] = __builtin_amdgcn_mfma_f32_16x16x32_f16(
                        ah[mt], bh[nt], aM[mt][nt], 0, 0, 0);
                    aX[mt][nt] = __builtin_amdgcn_mfma_f32_16x16x32_f16(
                        ah[mt], bl[nt], aX[mt][nt], 0, 0, 0);
                    aY[mt][nt] = __builtin_amdgcn_mfma_f32_16x16x32_f16(
                        al[mt], bh[nt], aY[mt][nt], 0, 0, 0);
                }
        }

        __syncthreads();
        #pragma unroll
        for (int mt = 0; mt < 2; ++mt)
            #pragma unroll
            for (int nt = 0; nt < 2; ++nt)
                #pragma unroll
                for (int r = 0; r < 4; ++r) {
                    float v = aM[mt][nt][r]
                            + (aX[mt][nt][r] + aY[mt][nt][r]) * SPLIT_INV;
                    float o = __shfl_xor(v, 1);
                    if ((lane & 1) == 0) {
                        int row = mt * 16 + q * 4 + r;
                        int bin = (wn * 32 + nt * 16 + lr) >> 1;
                        Sp[row][bin] = v * v + o * o;
                    }
                }
        __syncthreads();

        int kb0 = n0 >> 1;
        #pragma unroll
        for (int t = 0; t < 10; ++t) {
            int ks = lo10[t] > kb0 ? lo10[t] : kb0;
            int ke = hi10[t] < kb0 + 64 ? hi10[t] : kb0 + 64;
            const float* wrow = melfT + (size_t)(mg + 8 * t) * MTS;
            for (int k = ks; k < ke; ++k)
                accm[t] += Sp[mf][k - kb0] * wrow[k];
        }
    }

    {
        size_t row = (size_t)tile * 32 + mf;
        #pragma unroll
        for (int t = 0; t < 10; ++t)
            out[row * NMEL + mg + 8 * t] = logf(fmaxf(accm[t] * SCALE2, EPS_F));
    }
}

// ---------------- kernel 3: per-(batch,mel) sums over frames (fp32) ----------
__global__ __launch_bounds__(256) void k_mean(const float* __restrict__ out,
                                              float* __restrict__ means)
{
    __shared__ float red[240];
    int b = blockIdx.y, tid = threadIdx.x;
    int f0   = blockIdx.x * 375;
    int fend = min(f0 + 375, NFRAMES);
    int r = tid / 80, m = tid - r * 80;
    if (tid < 240) {
        float s = 0.f;
        const float* base = out + (size_t)b * NFRAMES * NMEL;
        for (int f = f0 + r; f < fend; f += 3)
            s += base[(size_t)f * NMEL + m];
        red[tid] = s;
    }
    __syncthreads();
    if (tid < 80)
        atomicAdd(&means[b * NMEL + tid], red[tid] + red[tid + 80] + red[tid + 160]);
}

// ---------------- kernel 4: subtract mean in-place (fp32) ----------
__global__ __launch_bounds__(256) void k_norm(const float* __restrict__ means,
                                              float* __restrict__ out)
{
    const int PER = NFRAMES * NMEL;           // 239,840
    int b = blockIdx.y;
    int e = blockIdx.x * 256 + threadIdx.x;
    if (e < PER) {
        int m = e % NMEL;
        size_t idx = (size_t)b * PER + e;
        out[idx] = out[idx] - means[b * NMEL + m] * (1.0f / (float)NFRAMES);
    }
}

// ---------------- launch ----------------
extern "C" void kernel_launch(void* const* d_in, const int* in_sizes, int n_in,
                              void* d_out, int out_size, void* d_ws, size_t ws_size,
                              hipStream_t stream)
{
    const float* wav    = (const float*)d_in[0];
    const float* window = (const float*)d_in[1];
    const float* melf   = (const float*)d_in[2];
    const float* dcos   = (const float*)d_in[3];
    const float* dsin   = (const float*)d_in[4];
    float* out = (float*)d_out;

    // ws layout:
    //   means fp32 32*80   @ 0        (10,240)
    //   mlo   int  80      @ 10,240   (320)
    //   mhi   int  80      @ 10,560   (320)
    //   melfT fp32 80*260  @ 10,880   (83,200)   -> 94,080
    //   Bh    f16  k-chunked 52*512*8 @ 94,208   (425,984)  -> 520,192
    //   Bl    f16  k-chunked 52*512*8 @ 520,192  (425,984)  -> 946,176
    char* ws = (char*)d_ws;
    float*     means = (float*)ws;
    int*       mlo   = (int*)(ws + 10240);
    int*       mhi   = (int*)(ws + 10560);
    float*     melfT = (float*)(ws + 10880);
    _Float16*  Bh    = (_Float16*)(ws + 94208);
    _Float16*  Bl    = (_Float16*)(ws + 520192);

    const int pre = (ws_size >= 946176) ? 1 : 0;

    FbankWrapper_14285061226526_kernel<<<10, 256, 0, stream>>>(means);
    k_prep<<<184, 256, 0, stream>>>(melf, dcos, dsin, mlo, mhi, melfT, Bh, Bl, pre);
    if (pre) {
        k_main_pre<<<2998, 256, 0, stream>>>(wav, window, melfT, mlo, mhi, Bh, Bl, out);
    } else {
        k_main<<<2998, 256, 0, stream>>>(wav, window, melfT, mlo, mhi, dcos, dsin, out);
    }
    k_mean<<<dim3(8, BATCH), 256, 0, stream>>>(out, means);
    k_norm<<<dim3((NFRAMES * NMEL + 255) / 256, BATCH), 256, 0, stream>>>(means, out);
}

// Round 5
// 301.097 us; speedup vs baseline: 1.7128x; 1.1673x over previous
//
#include <hip/hip_runtime.h>

// ---------------- problem constants ----------------
#define BATCH     32
#define T_SAMP    480000
#define NFRAMES   2998
#define KLEN      400
#define KA        416             // 13*32 ; k 400..415 zero-padded
#define NMEL      80
#define EPS_F     1.1920928955078125e-07f
#define SCALE2    1073741824.0f   // 32768^2, re-applied before log (A unscaled)
#define SPLIT_S   2048.0f         // lo-plane scale (keeps lo in fp16 normal range)
#define SPLIT_INV 4.8828125e-4f   // 1/2048
#define MTS       260             // melfT row stride (floats)

typedef _Float16 f16x8 __attribute__((ext_vector_type(8)));
typedef float    f32x4 __attribute__((ext_vector_type(4)));

// ---------------- kernel 0: zero the means accumulator (name kept for harness) --
__global__ __launch_bounds__(256) void FbankWrapper_14285061226526_kernel(float* means)
{
    int i = blockIdx.x * 256 + threadIdx.x;
    if (i < BATCH * NMEL) means[i] = 0.f;
}

// ---------------- kernel 1: fused setup ----------------------------------------
// blocks 0..79   : melfT row m = transpose of melf col m + per-mel lo/hi ranges
// blocks 80..183 : pre-split DFT basis into fp16 hi/lo planes, K-CHUNKED layout:
//                  elem (n,k) at ((k>>3)*512 + n)*8 + (k&7)  [n = re/im-interleaved
//                  col, k = sample index 0..415]. Adjacent lanes (n,n+1) are 16 B
//                  apart -> fully coalesced B loads in k_main.
__global__ __launch_bounds__(256) void k_prep(const float* __restrict__ melf,
                                              const float* __restrict__ dcos,
                                              const float* __restrict__ dsin,
                                              int* __restrict__ mlo,
                                              int* __restrict__ mhi,
                                              float* __restrict__ melfT,
                                              _Float16* __restrict__ Bh,
                                              _Float16* __restrict__ Bl,
                                              int pre)
{
    const int bid = blockIdx.x;
    const int tid = threadIdx.x;

    if (bid < 80) {
        __shared__ int slo, shi;
        if (tid == 0) { slo = 256; shi = 0; }
        __syncthreads();
        const int m = bid;
        float w = melf[(size_t)tid * NMEL + m];
        melfT[(size_t)m * MTS + tid] = w;
        int lom = (w > 0.f) ? tid : 256;
        int him = (w > 0.f) ? tid + 1 : 0;
        if (tid == 0) {
            float w2 = melf[(size_t)256 * NMEL + m];
            melfT[(size_t)m * MTS + 256] = w2;
            if (w2 > 0.f) { lom = 256 < lom ? 256 : lom; him = 257; }
            melfT[(size_t)m * MTS + 257] = 0.f;
            melfT[(size_t)m * MTS + 258] = 0.f;
            melfT[(size_t)m * MTS + 259] = 0.f;
        }
        atomicMin(&slo, lom);
        atomicMax(&shi, him);
        __syncthreads();
        if (tid == 0) { mlo[m] = slo; mhi[m] = shi; }
        return;
    }

    if (!pre) return;
    int id = (bid - 80) * 256 + tid;          // 0..26623 = 52 chunks * 512 cols
    if (id >= 52 * 512) return;
    int c = id >> 9;                          // k-chunk 0..51
    int n = id & 511;                         // col
    int k = c * 8;
    const float* src = ((n & 1) ? dsin : dcos) + (size_t)(n >> 1) * 512 + k;
    f16x8 hv, lv;
    #pragma unroll
    for (int j = 0; j < 8; ++j) {
        float v = src[j];
        _Float16 h = (_Float16)v;
        hv[j] = h;
        lv[j] = (_Float16)((v - (float)h) * SPLIT_S);
    }
    *(f16x8*)(Bh + (size_t)id * 8) = hv;      // ((c*512)+n)*8
    *(f16x8*)(Bl + (size_t)id * 8) = lv;
}

// ---------------- kernel 2 (fast path): 512-thread TLP version -----------------
// one block = 32 frames, 8 waves; wave w owns a 32-col strip; 2 passes of 256
// cols cover the 512 DFT cols. LDS 71,168 B -> 2 blocks/CU = 16 waves/CU =
// 4 waves/SIMD: latency hidden by TLP (ILP pipelining was collapsed by the
// compiler in rounds 3-4; VGPR stayed 88). B pre-split + k-chunked (coalesced).
// C = Ah*Bh + (Al*Bh + Ah*Bl)/2048, merged correction accumulator.
__global__ __launch_bounds__(512, 4) void k_main_pre(const float* __restrict__ wav,
                                                     const float* __restrict__ window,
                                                     const float* __restrict__ melfT,
                                                     const int* __restrict__ mlo,
                                                     const int* __restrict__ mhi,
                                                     const _Float16* __restrict__ Bh,
                                                     const _Float16* __restrict__ Bl,
                                                     float* __restrict__ out)
{
    __shared__ __align__(16) _Float16 Ah[32][424];   // 27,136 B
    __shared__ __align__(16) _Float16 Al[32][424];   // 27,136 B
    __shared__ __align__(16) float    Sp[32][132];   // 16,896 B  (71,168 total)

    const int tid  = threadIdx.x;
    const int lane = tid & 63;
    const int wid  = tid >> 6;              // wave 0..7
    const int tile = blockIdx.x;            // 0..2997

    // ---- prep: 16 threads per frame; mean via 16-lane shuffle; split hi/lo ----
    {
        int fr = tid >> 4, og = tid & 15;
        int fb = tile * 32 + fr;
        int b  = fb / NFRAMES;
        int f  = fb - b * NFRAMES;
        const float* sig = wav + (size_t)b * T_SAMP + (size_t)f * 160;

        float s = 0.f;
        #pragma unroll
        for (int i = 0; i < 4; ++i) {
            int k0 = og * 8 + 128 * i;
            if (k0 < KLEN) {
                float4 x0 = *(const float4*)(sig + k0);
                float4 x1 = *(const float4*)(sig + k0 + 4);
                s += x0.x + x0.y + x0.z + x0.w + x1.x + x1.y + x1.z + x1.w;
            }
        }
        s += __shfl_xor(s, 1);
        s += __shfl_xor(s, 2);
        s += __shfl_xor(s, 4);
        s += __shfl_xor(s, 8);
        float mean = s * (1.0f / (float)KLEN);

        #pragma unroll
        for (int i = 0; i < 4; ++i) {
            int k0 = og * 8 + 128 * i;
            if (k0 < KA) {
                f16x8 hv, lv;
                if (k0 < KLEN) {
                    float4 x0 = *(const float4*)(sig + k0);
                    float4 x1 = *(const float4*)(sig + k0 + 4);
                    float4 w0 = *(const float4*)(window + k0);
                    float4 w1 = *(const float4*)(window + k0 + 4);
                    float xm1 = (k0 > 0) ? sig[k0 - 1] : x0.x;
                    float xs[8] = {x0.x, x0.y, x0.z, x0.w, x1.x, x1.y, x1.z, x1.w};
                    float wv[8] = {w0.x, w0.y, w0.z, w0.w, w1.x, w1.y, w1.z, w1.w};
                    #pragma unroll
                    for (int j = 0; j < 8; ++j) {
                        float xp = (j == 0) ? xm1 : xs[j - 1];
                        float y  = (xs[j] - 0.97f * xp - 0.03f * mean) * wv[j];
                        _Float16 h = (_Float16)y;
                        hv[j] = h;
                        lv[j] = (_Float16)((y - (float)h) * SPLIT_S);
                    }
                } else {
                    #pragma unroll
                    for (int j = 0; j < 8; ++j) { hv[j] = (_Float16)0.f; lv[j] = (_Float16)0.f; }
                }
                *(f16x8*)&Ah[fr][k0] = hv;
                *(f16x8*)&Al[fr][k0] = lv;
            }
        }
    }
    __syncthreads();                        // A planes ready

    const int q  = lane >> 4, lr = lane & 15;
    const int mf = tid & 31;                // mel: frame
    const int mg = tid >> 5;                // mel: 0..15 (mels mg+16t, t=0..4)

    int lo5[5], hi5[5];
    #pragma unroll
    for (int t = 0; t < 5; ++t) { lo5[t] = mlo[mg + 16 * t]; hi5[t] = mhi[mg + 16 * t]; }

    float accm[5];
    #pragma unroll
    for (int t = 0; t < 5; ++t) accm[t] = 0.f;

    for (int p = 0; p < 2; ++p) {
        const int n0 = p * 256;
        f32x4 aM[2][2], aC[2][2];
        #pragma unroll
        for (int mt = 0; mt < 2; ++mt)
            #pragma unroll
            for (int nt = 0; nt < 2; ++nt) {
                aM[mt][nt] = (f32x4){0.f, 0.f, 0.f, 0.f};
                aC[mt][nt] = (f32x4){0.f, 0.f, 0.f, 0.f};
            }

        // per-lane B base in k-chunked layout: (n,k) -> ((k>>3)*512 + n)*8 + (k&7)
        // lane covers k = kk + q*8 .. +8 -> offset (kk/8 + q)*4096 + n*8;
        // per 32-k step advance = 4*4096 = 16384 f16.
        const _Float16* bph[2];
        const _Float16* blp[2];
        #pragma unroll
        for (int nt = 0; nt < 2; ++nt) {
            int n = n0 + wid * 32 + nt * 16 + lr;
            size_t off = (size_t)q * 4096 + (size_t)n * 8;
            bph[nt] = Bh + off;
            blp[nt] = Bl + off;
        }

        for (int s = 0; s < 13; ++s) {
            const int kk = s * 32;
            f16x8 ah[2], al[2], bh[2], bl[2];
            #pragma unroll
            for (int mt = 0; mt < 2; ++mt) {
                ah[mt] = *(const f16x8*)&Ah[mt * 16 + lr][kk + q * 8];
                al[mt] = *(const f16x8*)&Al[mt * 16 + lr][kk + q * 8];
            }
            #pragma unroll
            for (int nt = 0; nt < 2; ++nt) {
                bh[nt] = *(const f16x8*)(bph[nt] + (size_t)s * 16384);
                bl[nt] = *(const f16x8*)(blp[nt] + (size_t)s * 16384);
            }
            #pragma unroll
            for (int mt = 0; mt < 2; ++mt)
                #pragma unroll
                for (int nt = 0; nt < 2; ++nt)
                    aM[mt][nt] = __builtin_amdgcn_mfma_f32_16x16x32_f16(
                        ah[mt], bh[nt], aM[mt][nt], 0, 0, 0);
            #pragma unroll
            for (int mt = 0; mt < 2; ++mt)
                #pragma unroll
                for (int nt = 0; nt < 2; ++nt)
                    aC[mt][nt] = __builtin_amdgcn_mfma_f32_16x16x32_f16(
                        al[mt], bh[nt], aC[mt][nt], 0, 0, 0);
            #pragma unroll
            for (int mt = 0; mt < 2; ++mt)
                #pragma unroll
                for (int nt = 0; nt < 2; ++nt)
                    aC[mt][nt] = __builtin_amdgcn_mfma_f32_16x16x32_f16(
                        ah[mt], bl[nt], aC[mt][nt], 0, 0, 0);
        }

        // ---- spectrum epilogue: combine split planes, pair re/im via shfl ----
        __syncthreads();                    // prior pass's mel Sp-reads done
        #pragma unroll
        for (int mt = 0; mt < 2; ++mt)
            #pragma unroll
            for (int nt = 0; nt < 2; ++nt)
                #pragma unroll
                for (int r = 0; r < 4; ++r) {
                    float v = aM[mt][nt][r] + aC[mt][nt][r] * SPLIT_INV;
                    float o = __shfl_xor(v, 1);
                    if ((lane & 1) == 0) {
                        int row = mt * 16 + q * 4 + r;                // frame 0..31
                        int bin = (wid * 32 + nt * 16 + lr) >> 1;     // 0..127
                        Sp[row][bin] = v * v + o * o;
                    }
                }
        __syncthreads();                    // Sp visible

        // ---- sparse mel, vectorized: melfT is 0 outside [lo,hi) so aligned
        // float4 over-reads are numerically exact. Sp col idx <= 130; melfT
        // tail 257..259 zeroed in k_prep.
        int kb0 = p * 128;
        #pragma unroll
        for (int t = 0; t < 5; ++t) {
            int ks = lo5[t] > kb0 ? lo5[t] : kb0;
            int ke = hi5[t] < kb0 + 128 ? hi5[t] : kb0 + 128;
            const float* wrow = melfT + (size_t)(mg + 16 * t) * MTS;
            for (int k4 = ks & ~3; k4 < ke; k4 += 4) {
                f32x4  sv = *(const f32x4*)&Sp[mf][k4 - kb0];
                float4 wv = *(const float4*)(wrow + k4);
                accm[t] += sv[0] * wv.x + sv[1] * wv.y + sv[2] * wv.z + sv[3] * wv.w;
            }
        }
    }

    // ---- re-apply 32768^2, log, fp32 store ----
    {
        size_t row = (size_t)tile * 32 + mf;
        #pragma unroll
        for (int t = 0; t < 5; ++t)
            out[row * NMEL + mg + 16 * t] = logf(fmaxf(accm[t] * SCALE2, EPS_F));
    }
}

// ---------------- kernel 2 (fallback): in-register B split (round-1 kernel) ---
__global__ __launch_bounds__(256) void k_main(const float* __restrict__ wav,
                                              const float* __restrict__ window,
                                              const float* __restrict__ melfT,
                                              const int* __restrict__ mlo,
                                              const int* __restrict__ mhi,
                                              const float* __restrict__ dcos,
                                              const float* __restrict__ dsin,
                                              float* __restrict__ out)
{
    __shared__ __align__(16) _Float16 Ah[32][424];
    __shared__ __align__(16) _Float16 Al[32][424];
    __shared__ __align__(16) float    Sp[32][66];

    const int tid  = threadIdx.x;
    const int lane = tid & 63;
    const int wid  = tid >> 6;
    const int tile = blockIdx.x;

    {
        int fr = tid >> 3, og = tid & 7;
        int fb = tile * 32 + fr;
        int b  = fb / NFRAMES;
        int f  = fb - b * NFRAMES;
        const float* sig = wav + (size_t)b * T_SAMP + (size_t)f * 160;

        float s = 0.f;
        #pragma unroll
        for (int i = 0; i < 7; ++i) {
            int k0 = og * 8 + 64 * i;
            if (k0 < KLEN) {
                float4 x0 = *(const float4*)(sig + k0);
                float4 x1 = *(const float4*)(sig + k0 + 4);
                s += x0.x + x0.y + x0.z + x0.w + x1.x + x1.y + x1.z + x1.w;
            }
        }
        s += __shfl_xor(s, 1);
        s += __shfl_xor(s, 2);
        s += __shfl_xor(s, 4);
        float mean = s * (1.0f / (float)KLEN);

        #pragma unroll
        for (int i = 0; i < 7; ++i) {
            int k0 = og * 8 + 64 * i;
            if (k0 < KA) {
                f16x8 hv, lv;
                if (k0 < KLEN) {
                    float4 x0 = *(const float4*)(sig + k0);
                    float4 x1 = *(const float4*)(sig + k0 + 4);
                    float4 w0 = *(const float4*)(window + k0);
                    float4 w1 = *(const float4*)(window + k0 + 4);
                    float xm1 = (k0 > 0) ? sig[k0 - 1] : x0.x;
                    float xs[8] = {x0.x, x0.y, x0.z, x0.w, x1.x, x1.y, x1.z, x1.w};
                    float wv[8] = {w0.x, w0.y, w0.z, w0.w, w1.x, w1.y, w1.z, w1.w};
                    #pragma unroll
                    for (int j = 0; j < 8; ++j) {
                        float xp = (j == 0) ? xm1 : xs[j - 1];
                        float y  = (xs[j] - 0.97f * xp - 0.03f * mean) * wv[j];
                        _Float16 h = (_Float16)y;
                        hv[j] = h;
                        lv[j] = (_Float16)((y - (float)h) * SPLIT_S);
                    }
                } else {
                    #pragma unroll
                    for (int j = 0; j < 8; ++j) { hv[j] = (_Float16)0.f; lv[j] = (_Float16)0.f; }
                }
                *(f16x8*)&Ah[fr][k0] = hv;
                *(f16x8*)&Al[fr][k0] = lv;
            }
        }
    }
    __syncthreads();

    const int wn = wid;
    const int q  = lane >> 4, lr = lane & 15;
    const int mf = tid & 31;
    const int mg = tid >> 5;

    int lo10[10], hi10[10];
    #pragma unroll
    for (int t = 0; t < 10; ++t) { lo10[t] = mlo[mg + 8 * t]; hi10[t] = mhi[mg + 8 * t]; }

    float accm[10];
    #pragma unroll
    for (int t = 0; t < 10; ++t) accm[t] = 0.f;

    for (int n0 = 0; n0 < 512; n0 += 128) {
        f32x4 aM[2][2], aX[2][2], aY[2][2];
        #pragma unroll
        for (int mt = 0; mt < 2; ++mt)
            #pragma unroll
            for (int nt = 0; nt < 2; ++nt) {
                aM[mt][nt] = (f32x4){0.f, 0.f, 0.f, 0.f};
                aX[mt][nt] = (f32x4){0.f, 0.f, 0.f, 0.f};
                aY[mt][nt] = (f32x4){0.f, 0.f, 0.f, 0.f};
            }

        const float* bp[2];
        #pragma unroll
        for (int nt = 0; nt < 2; ++nt) {
            int n = n0 + wn * 32 + nt * 16 + lr;
            bp[nt] = ((n & 1) ? dsin : dcos) + (size_t)(n >> 1) * 512 + q * 8;
        }

        for (int kk = 0; kk < KA; kk += 32) {
            f16x8 ah[2], al[2], bh[2], bl[2];
            #pragma unroll
            for (int mt = 0; mt < 2; ++mt) {
                ah[mt] = *(const f16x8*)&Ah[mt * 16 + lr][kk + q * 8];
                al[mt] = *(const f16x8*)&Al[mt * 16 + lr][kk + q * 8];
            }
            #pragma unroll
            for (int nt = 0; nt < 2; ++nt) {
                float4 b0 = *(const float4*)(bp[nt] + kk);
                float4 b1 = *(const float4*)(bp[nt] + kk + 4);
                float bv[8] = {b0.x, b0.y, b0.z, b0.w, b1.x, b1.y, b1.z, b1.w};
                #pragma unroll
                for (int j = 0; j < 8; ++j) {
                    _Float16 h = (_Float16)bv[j];
                    bh[nt][j] = h;
                    bl[nt][j] = (_Float16)((bv[j] - (float)h) * SPLIT_S);
                }
            }
            #pragma unroll
            for (int mt = 0; mt < 2; ++mt)
                #pragma unroll
                for (int nt = 0; nt < 2; ++nt) {
                    aM[mt][nt] = __builtin_amdgcn_mfma_f32_16x16x32_f16(
                        ah[mt], bh[nt], aM[mt][nt], 0, 0, 0);
                    aX[mt][nt] = __builtin_amdgcn_mfma_f32_16x16x32_f16(
                        ah[mt], bl[nt], aX[mt][nt], 0, 0, 0);
                    aY[mt][nt] = __builtin_amdgcn_mfma_f32_16x16x32_f16(
                        al[mt], bh[nt], aY[mt][nt], 0, 0, 0);
                }
        }

        __syncthreads();
        #pragma unroll
        for (int mt = 0; mt < 2; ++mt)
            #pragma unroll
            for (int nt = 0; nt < 2; ++nt)
                #pragma unroll
                for (int r = 0; r < 4; ++r) {
                    float v = aM[mt][nt][r]
                            + (aX[mt][nt][r] + aY[mt][nt][r]) * SPLIT_INV;
                    float o = __shfl_xor(v, 1);
                    if ((lane & 1) == 0) {
                        int row = mt * 16 + q * 4 + r;
                        int bin = (wn * 32 + nt * 16 + lr) >> 1;
                        Sp[row][bin] = v * v + o * o;
                    }
                }
        __syncthreads();

        int kb0 = n0 >> 1;
        #pragma unroll
        for (int t = 0; t < 10; ++t) {
            int ks = lo10[t] > kb0 ? lo10[t] : kb0;
            int ke = hi10[t] < kb0 + 64 ? hi10[t] : kb0 + 64;
            const float* wrow = melfT + (size_t)(mg + 8 * t) * MTS;
            for (int k = ks; k < ke; ++k)
                accm[t] += Sp[mf][k - kb0] * wrow[k];
        }
    }

    {
        size_t row = (size_t)tile * 32 + mf;
        #pragma unroll
        for (int t = 0; t < 10; ++t)
            out[row * NMEL + mg + 8 * t] = logf(fmaxf(accm[t] * SCALE2, EPS_F));
    }
}

// ---------------- kernel 3: per-(batch,mel) sums over frames (fp32) ----------
__global__ __launch_bounds__(256) void k_mean(const float* __restrict__ out,
                                              float* __restrict__ means)
{
    __shared__ float red[240];
    int b = blockIdx.y, tid = threadIdx.x;
    int f0   = blockIdx.x * 375;
    int fend = min(f0 + 375, NFRAMES);
    int r = tid / 80, m = tid - r * 80;
    if (tid < 240) {
        float s = 0.f;
        const float* base = out + (size_t)b * NFRAMES * NMEL;
        for (int f = f0 + r; f < fend; f += 3)
            s += base[(size_t)f * NMEL + m];
        red[tid] = s;
    }
    __syncthreads();
    if (tid < 80)
        atomicAdd(&means[b * NMEL + tid], red[tid] + red[tid + 80] + red[tid + 160]);
}

// ---------------- kernel 4: subtract mean in-place (fp32) ----------
__global__ __launch_bounds__(256) void k_norm(const float* __restrict__ means,
                                              float* __restrict__ out)
{
    const int PER = NFRAMES * NMEL;           // 239,840
    int b = blockIdx.y;
    int e = blockIdx.x * 256 + threadIdx.x;
    if (e < PER) {
        int m = e % NMEL;
        size_t idx = (size_t)b * PER + e;
        out[idx] = out[idx] - means[b * NMEL + m] * (1.0f / (float)NFRAMES);
    }
}

// ---------------- launch ----------------
extern "C" void kernel_launch(void* const* d_in, const int* in_sizes, int n_in,
                              void* d_out, int out_size, void* d_ws, size_t ws_size,
                              hipStream_t stream)
{
    const float* wav    = (const float*)d_in[0];
    const float* window = (const float*)d_in[1];
    const float* melf   = (const float*)d_in[2];
    const float* dcos   = (const float*)d_in[3];
    const float* dsin   = (const float*)d_in[4];
    float* out = (float*)d_out;

    // ws layout:
    //   means fp32 32*80   @ 0        (10,240)
    //   mlo   int  80      @ 10,240   (320)
    //   mhi   int  80      @ 10,560   (320)
    //   melfT fp32 80*260  @ 10,880   (83,200)   -> 94,080
    //   Bh    f16  k-chunked 52*512*8 @ 94,208   (425,984)  -> 520,192
    //   Bl    f16  k-chunked 52*512*8 @ 520,192  (425,984)  -> 946,176
    char* ws = (char*)d_ws;
    float*     means = (float*)ws;
    int*       mlo   = (int*)(ws + 10240);
    int*       mhi   = (int*)(ws + 10560);
    float*     melfT = (float*)(ws + 10880);
    _Float16*  Bh    = (_Float16*)(ws + 94208);
    _Float16*  Bl    = (_Float16*)(ws + 520192);

    const int pre = (ws_size >= 946176) ? 1 : 0;

    FbankWrapper_14285061226526_kernel<<<10, 256, 0, stream>>>(means);
    k_prep<<<184, 256, 0, stream>>>(melf, dcos, dsin, mlo, mhi, melfT, Bh, Bl, pre);
    if (pre) {
        k_main_pre<<<2998, 512, 0, stream>>>(wav, window, melfT, mlo, mhi, Bh, Bl, out);
    } else {
        k_main<<<2998, 256, 0, stream>>>(wav, window, melfT, mlo, mhi, dcos, dsin, out);
    }
    k_mean<<<dim3(8, BATCH), 256, 0, stream>>>(out, means);
    k_norm<<<dim3((NFRAMES * NMEL + 255) / 256, BATCH), 256, 0, stream>>>(means, out);
}

// Round 6
// 267.509 us; speedup vs baseline: 1.9279x; 1.1256x over previous
//
#include <hip/hip_runtime.h>

// ---------------- problem constants ----------------
#define BATCH     32
#define T_SAMP    480000
#define NFRAMES   2998
#define KLEN      400
#define KF        256             // folded K: t and t+256 combined (x[t>=400]=0)
#define NMEL      80
#define EPS_F     1.1920928955078125e-07f
#define SCALE2    1073741824.0f   // 32768^2, re-applied before log (A unscaled)
#define SPLIT_S   2048.0f         // lo-plane scale
#define SPLIT_INV 4.8828125e-4f   // 1/2048
#define MTE       132             // per-parity mel filter row stride (floats)

typedef _Float16 f16x8 __attribute__((ext_vector_type(8)));
typedef float    f32x4 __attribute__((ext_vector_type(4)));

// ---------------- kernel 0: zero the means accumulator (name kept for harness) --
__global__ __launch_bounds__(256) void FbankWrapper_14285061226526_kernel(float* means)
{
    int i = blockIdx.x * 256 + threadIdx.x;
    if (i < BATCH * NMEL) means[i] = 0.f;
}

// ---------------- kernel 1: fused setup -----------------------------------------
// DFT fold: B[bin][k+256] = (-1)^bin B[bin][k]  ->  even bins consume xe=y[k]+y[k+256],
// odd bins consume xo=y[k]-y[k+256], K=256.
// Even group (256 cols): c=0 -> bin0 re; c=1 -> bin256 re (their sin rows are ~0 and
// their mel weights are exactly 0); c>=2 -> bin=2*(c>>1), re/im by c&1.
// Odd group (256 cols): bin=2*(c>>1)+1, re/im by c&1.
// B planes stored fp16 hi/lo, K-CHUNKED: elem (c,k) at ((k>>3)*256 + c)*8 + (k&7).
// blocks 0..79: per-parity mel filter rows (melfTe/melfTo) + slot ranges.
// blocks 80..143: B split/fold gather from the PROVIDED dcos/dsin tables.
__global__ __launch_bounds__(256) void k_prep(const float* __restrict__ melf,
                                              const float* __restrict__ dcos,
                                              const float* __restrict__ dsin,
                                              int* __restrict__ loE, int* __restrict__ hiE,
                                              int* __restrict__ loO, int* __restrict__ hiO,
                                              float* __restrict__ melfTe,
                                              float* __restrict__ melfTo,
                                              _Float16* __restrict__ Bhe, _Float16* __restrict__ Ble,
                                              _Float16* __restrict__ Bho, _Float16* __restrict__ Blo)
{
    const int bid = blockIdx.x;
    const int tid = threadIdx.x;

    if (bid < 80) {
        __shared__ int sE0, sE1, sO0, sO1;
        if (tid == 0) { sE0 = 999; sE1 = 0; sO0 = 999; sO1 = 0; }
        __syncthreads();
        const int m = bid;
        if (tid < 129) {                       // even slots: bin 0,2,...,254,256
            int bin = (tid == 0) ? 0 : (tid == 128) ? 256 : 2 * tid;
            float w = melf[(size_t)bin * NMEL + m];
            melfTe[(size_t)m * MTE + tid] = w;
            if (w > 0.f) { atomicMin(&sE0, tid); atomicMax(&sE1, tid + 1); }
        }
        if (tid < 128) {                       // odd slots: bin 1,3,...,255
            float w = melf[(size_t)(2 * tid + 1) * NMEL + m];
            melfTo[(size_t)m * MTE + tid] = w;
            if (w > 0.f) { atomicMin(&sO0, tid); atomicMax(&sO1, tid + 1); }
        }
        if (tid == 0) {
            melfTe[(size_t)m * MTE + 129] = 0.f;
            melfTe[(size_t)m * MTE + 130] = 0.f;
            melfTe[(size_t)m * MTE + 131] = 0.f;
            melfTo[(size_t)m * MTE + 128] = 0.f;
            melfTo[(size_t)m * MTE + 129] = 0.f;
            melfTo[(size_t)m * MTE + 130] = 0.f;
            melfTo[(size_t)m * MTE + 131] = 0.f;
        }
        __syncthreads();
        if (tid == 0) { loE[m] = sE0; hiE[m] = sE1; loO[m] = sO0; hiO[m] = sO1; }
        return;
    }

    int id = (bid - 80) * 256 + tid;           // 2 groups * 32 chunks * 256 cols
    if (id >= 16384) return;
    int g  = id >> 13;                         // 0 = even group, 1 = odd group
    int r  = id & 8191;
    int ch = r >> 8;                           // k-chunk 0..31
    int c  = r & 255;                          // col
    int k  = ch * 8;
    int bin; int sn;
    if (g == 0) { bin = (c == 0) ? 0 : (c == 1) ? 256 : 2 * (c >> 1); sn = (c >= 2) && (c & 1); }
    else        { bin = 2 * (c >> 1) + 1;                             sn = c & 1; }
    const float* src = (sn ? dsin : dcos) + (size_t)bin * 512 + k;
    f16x8 hv, lv;
    #pragma unroll
    for (int j = 0; j < 8; ++j) {
        float v = src[j];
        _Float16 h = (_Float16)v;
        hv[j] = h;
        lv[j] = (_Float16)((v - (float)h) * SPLIT_S);
    }
    size_t off = ((size_t)ch * 256 + c) * 8;
    *(f16x8*)((g ? Bho : Bhe) + off) = hv;
    *(f16x8*)((g ? Blo : Ble) + off) = lv;
}

// ---------------- helpers for k_main prep ----------------
__device__ inline void y8_compute(const float* __restrict__ sig,
                                  const float* __restrict__ window,
                                  int k0, float mean, float ys[8])
{
    float4 x0 = *(const float4*)(sig + k0);
    float4 x1 = *(const float4*)(sig + k0 + 4);
    float4 w0 = *(const float4*)(window + k0);
    float4 w1 = *(const float4*)(window + k0 + 4);
    float xm1 = (k0 > 0) ? sig[k0 - 1] : x0.x;
    float xs[8] = {x0.x, x0.y, x0.z, x0.w, x1.x, x1.y, x1.z, x1.w};
    float wv[8] = {w0.x, w0.y, w0.z, w0.w, w1.x, w1.y, w1.z, w1.w};
    #pragma unroll
    for (int j = 0; j < 8; ++j) {
        float xp = (j == 0) ? xm1 : xs[j - 1];
        ys[j] = (xs[j] - 0.97f * xp - 0.03f * mean) * wv[j];
    }
}

__device__ inline void split_store(_Float16* dh, _Float16* dl, const float ys[8])
{
    f16x8 hv, lv;
    #pragma unroll
    for (int j = 0; j < 8; ++j) {
        _Float16 h = (_Float16)ys[j];
        hv[j] = h;
        lv[j] = (_Float16)((ys[j] - (float)h) * SPLIT_S);
    }
    *(f16x8*)dh = hv;
    *(f16x8*)dl = lv;
}

// ---------------- kernel 2: folded split-fp16 MFMA DFT + spectrum + mel ---------
// one block = 32 frames, 8 waves, 512 threads, 2 blocks/CU (72,704 B LDS).
// pass 0 = even bins (Ae planes, Bhe/Ble), pass 1 = odd bins (Ao for k<160 which
// shares its tail with Ae since xo[k]=xe[k]=y[k] for k>=144; Bho/Blo).
// C = Ah*Bh + (Al*Bh + Ah*Bl)/2048, merged correction accumulator.
__global__ __launch_bounds__(512, 4) void k_main_pre(const float* __restrict__ wav,
                                                     const float* __restrict__ window,
                                                     const float* __restrict__ melfTe,
                                                     const float* __restrict__ melfTo,
                                                     const int* __restrict__ loE,
                                                     const int* __restrict__ hiE,
                                                     const int* __restrict__ loO,
                                                     const int* __restrict__ hiO,
                                                     const _Float16* __restrict__ Bhe,
                                                     const _Float16* __restrict__ Ble,
                                                     const _Float16* __restrict__ Bho,
                                                     const _Float16* __restrict__ Blo,
                                                     float* __restrict__ out)
{
    __shared__ __align__(16) _Float16 Aeh[32][264];  // 16,896 B  (stride 264: 2-way banks)
    __shared__ __align__(16) _Float16 Ael[32][264];  // 16,896 B
    __shared__ __align__(16) _Float16 Aoh[32][168];  // 10,752 B  (k<160 only; 168: 2-way)
    __shared__ __align__(16) _Float16 Aol[32][168];  // 10,752 B
    __shared__ __align__(16) float    Sp[32][136];   // 17,408 B  (total 72,704)

    const int tid  = threadIdx.x;
    const int lane = tid & 63;
    const int wid  = tid >> 6;              // wave 0..7
    const int tile = blockIdx.x;            // 0..2997

    // ---- prep: 16 threads/frame; mean via shuffle; fold + split to 4 planes ----
    {
        int fr = tid >> 4, og = tid & 15;
        int fb = tile * 32 + fr;
        int b  = fb / NFRAMES;
        int f  = fb - b * NFRAMES;
        const float* sig = wav + (size_t)b * T_SAMP + (size_t)f * 160;

        float s = 0.f;
        #pragma unroll
        for (int i = 0; i < 4; ++i) {
            int k0 = og * 8 + 128 * i;
            if (k0 < KLEN) {
                float4 x0 = *(const float4*)(sig + k0);
                float4 x1 = *(const float4*)(sig + k0 + 4);
                s += x0.x + x0.y + x0.z + x0.w + x1.x + x1.y + x1.z + x1.w;
            }
        }
        s += __shfl_xor(s, 1);
        s += __shfl_xor(s, 2);
        s += __shfl_xor(s, 4);
        s += __shfl_xor(s, 8);
        float mean = s * (1.0f / (float)KLEN);

        if (tid < 32) {                     // Sp over-read tail must be finite
            #pragma unroll
            for (int j = 128; j < 136; ++j) Sp[tid][j] = 0.f;
        }

        // fold tasks: chunks og and og+16 (8 samples each, k0 = 8c)
        #pragma unroll
        for (int t2 = 0; t2 < 2; ++t2) {
            int c  = og + 16 * t2;          // 0..31
            int k0 = c * 8;                 // 0..248
            float ys[8];
            y8_compute(sig, window, k0, mean, ys);
            if (c < 18) {                   // pairs with k0+256 (<400)
                float yb[8], ye[8], yo[8];
                y8_compute(sig, window, k0 + 256, mean, yb);
                #pragma unroll
                for (int j = 0; j < 8; ++j) { ye[j] = ys[j] + yb[j]; yo[j] = ys[j] - yb[j]; }
                split_store(&Aeh[fr][k0], &Ael[fr][k0], ye);
                split_store(&Aoh[fr][k0], &Aol[fr][k0], yo);
            } else {                        // x[k0+256]=0 -> xe=xo=y
                split_store(&Aeh[fr][k0], &Ael[fr][k0], ys);
                if (k0 < 160)
                    split_store(&Aoh[fr][k0], &Aol[fr][k0], ys);
            }
        }
    }
    __syncthreads();                        // A planes + Sp tail ready

    const int q  = lane >> 4, lr = lane & 15;
    const int mf = tid & 31;                // mel: frame
    const int mg = tid >> 5;                // mel: 0..15 (mels mg+16t, t=0..4)

    float accm[5];
    #pragma unroll
    for (int t = 0; t < 5; ++t) accm[t] = 0.f;

    #pragma unroll
    for (int p = 0; p < 2; ++p) {
        f32x4 aM[2][2], aC[2][2];
        #pragma unroll
        for (int mt = 0; mt < 2; ++mt)
            #pragma unroll
            for (int nt = 0; nt < 2; ++nt) {
                aM[mt][nt] = (f32x4){0.f, 0.f, 0.f, 0.f};
                aC[mt][nt] = (f32x4){0.f, 0.f, 0.f, 0.f};
            }

        const _Float16* Bh_ = p ? Bho : Bhe;
        const _Float16* Bl_ = p ? Blo : Ble;
        const _Float16* bph[2];
        const _Float16* blp[2];
        #pragma unroll
        for (int nt = 0; nt < 2; ++nt) {
            int c = wid * 32 + nt * 16 + lr;            // col within group, 0..255
            size_t off = (size_t)q * 2048 + (size_t)c * 8;
            bph[nt] = Bh_ + off;
            blp[nt] = Bl_ + off;
        }

        // ---- K loop: 8 steps of 32; pass1 reads Ao for k<160, Ae tail after ----
        #pragma unroll
        for (int s = 0; s < 8; ++s) {
            const int kk = s * 32;
            f16x8 ah[2], al[2], bh[2], bl[2];
            if (p == 0 || s >= 5) {
                #pragma unroll
                for (int mt = 0; mt < 2; ++mt) {
                    ah[mt] = *(const f16x8*)&Aeh[mt * 16 + lr][kk + q * 8];
                    al[mt] = *(const f16x8*)&Ael[mt * 16 + lr][kk + q * 8];
                }
            } else {
                #pragma unroll
                for (int mt = 0; mt < 2; ++mt) {
                    ah[mt] = *(const f16x8*)&Aoh[mt * 16 + lr][kk + q * 8];
                    al[mt] = *(const f16x8*)&Aol[mt * 16 + lr][kk + q * 8];
                }
            }
            #pragma unroll
            for (int nt = 0; nt < 2; ++nt) {
                bh[nt] = *(const f16x8*)(bph[nt] + (size_t)s * 8192);
                bl[nt] = *(const f16x8*)(blp[nt] + (size_t)s * 8192);
            }
            #pragma unroll
            for (int mt = 0; mt < 2; ++mt)
                #pragma unroll
                for (int nt = 0; nt < 2; ++nt)
                    aM[mt][nt] = __builtin_amdgcn_mfma_f32_16x16x32_f16(
                        ah[mt], bh[nt], aM[mt][nt], 0, 0, 0);
            #pragma unroll
            for (int mt = 0; mt < 2; ++mt)
                #pragma unroll
                for (int nt = 0; nt < 2; ++nt)
                    aC[mt][nt] = __builtin_amdgcn_mfma_f32_16x16x32_f16(
                        al[mt], bh[nt], aC[mt][nt], 0, 0, 0);
            #pragma unroll
            for (int mt = 0; mt < 2; ++mt)
                #pragma unroll
                for (int nt = 0; nt < 2; ++nt)
                    aC[mt][nt] = __builtin_amdgcn_mfma_f32_16x16x32_f16(
                        ah[mt], bl[nt], aC[mt][nt], 0, 0, 0);
        }

        // ---- spectrum epilogue: combine planes, pair re/im via shfl ----
        __syncthreads();                    // prior pass's mel Sp-reads done
        #pragma unroll
        for (int mt = 0; mt < 2; ++mt)
            #pragma unroll
            for (int nt = 0; nt < 2; ++nt)
                #pragma unroll
                for (int r = 0; r < 4; ++r) {
                    float v = aM[mt][nt][r] + aC[mt][nt][r] * SPLIT_INV;
                    float o = __shfl_xor(v, 1);
                    int row = mt * 16 + q * 4 + r;                 // frame 0..31
                    if (p == 0 && wid == 0 && nt == 0 && lr < 2) {
                        // even-group cols 0/1 = bin0/bin256 re-only (mel weight 0,
                        // but slots must be finite for vectorized over-reads)
                        Sp[row][lr ? 128 : 0] = v * v;
                    } else if ((lane & 1) == 0) {
                        int slot = (wid * 32 + nt * 16 + lr) >> 1; // 0..127 (1..127 p0)
                        Sp[row][slot] = v * v + o * o;
                    }
                }
        __syncthreads();                    // Sp visible

        // ---- mel partial-accumulate for this parity; zero-padded over-reads ----
        const float* mfT = p ? melfTo : melfTe;
        const int*   loP = p ? loO : loE;
        const int*   hiP = p ? hiO : hiE;
        #pragma unroll
        for (int t = 0; t < 5; ++t) {
            int m  = mg + 16 * t;
            int ks = loP[m], ke = hiP[m];
            const float* wrow = mfT + (size_t)m * MTE;
            for (int k4 = ks & ~3; k4 < ke; k4 += 4) {
                f32x4  sv = *(const f32x4*)&Sp[mf][k4];
                float4 wv = *(const float4*)(wrow + k4);
                accm[t] += sv[0] * wv.x + sv[1] * wv.y + sv[2] * wv.z + sv[3] * wv.w;
            }
        }
    }

    // ---- re-apply 32768^2, log, fp32 store ----
    {
        size_t row = (size_t)tile * 32 + mf;
        #pragma unroll
        for (int t = 0; t < 5; ++t)
            out[row * NMEL + mg + 16 * t] = logf(fmaxf(accm[t] * SCALE2, EPS_F));
    }
}

// ---------------- kernel 3: per-(batch,mel) sums over frames (fp32) ----------
__global__ __launch_bounds__(256) void k_mean(const float* __restrict__ out,
                                              float* __restrict__ means)
{
    __shared__ float red[240];
    int b = blockIdx.y, tid = threadIdx.x;
    int f0   = blockIdx.x * 375;
    int fend = min(f0 + 375, NFRAMES);
    int r = tid / 80, m = tid - r * 80;
    if (tid < 240) {
        float s = 0.f;
        const float* base = out + (size_t)b * NFRAMES * NMEL;
        for (int f = f0 + r; f < fend; f += 3)
            s += base[(size_t)f * NMEL + m];
        red[tid] = s;
    }
    __syncthreads();
    if (tid < 80)
        atomicAdd(&means[b * NMEL + tid], red[tid] + red[tid + 80] + red[tid + 160]);
}

// ---------------- kernel 4: subtract mean in-place (fp32) ----------
__global__ __launch_bounds__(256) void k_norm(const float* __restrict__ means,
                                              float* __restrict__ out)
{
    const int PER = NFRAMES * NMEL;           // 239,840
    int b = blockIdx.y;
    int e = blockIdx.x * 256 + threadIdx.x;
    if (e < PER) {
        int m = e % NMEL;
        size_t idx = (size_t)b * PER + e;
        out[idx] = out[idx] - means[b * NMEL + m] * (1.0f / (float)NFRAMES);
    }
}

// ---------------- launch ----------------
extern "C" void kernel_launch(void* const* d_in, const int* in_sizes, int n_in,
                              void* d_out, int out_size, void* d_ws, size_t ws_size,
                              hipStream_t stream)
{
    const float* wav    = (const float*)d_in[0];
    const float* window = (const float*)d_in[1];
    const float* melf   = (const float*)d_in[2];
    const float* dcos   = (const float*)d_in[3];
    const float* dsin   = (const float*)d_in[4];
    float* out = (float*)d_out;

    // ws layout (620,544 B; harness proved >= 946,176 usable in rounds 2-5):
    //   means  fp32 32*80        @ 0        (10,240)
    //   loE/hiE/loO/hiO int 80*4 @ 10,240   (1,280)
    //   melfTe fp32 80*132       @ 11,520   (42,240)
    //   melfTo fp32 80*132       @ 53,760   (42,240)  -> 96,000 (pad to 96,256)
    //   Bhe f16 32*256*8         @ 96,256   (131,072)
    //   Ble f16                  @ 227,328  (131,072)
    //   Bho f16                  @ 358,400  (131,072)
    //   Blo f16                  @ 489,472  (131,072) -> 620,544
    char* ws = (char*)d_ws;
    float*     means  = (float*)ws;
    int*       loE    = (int*)(ws + 10240);
    int*       hiE    = (int*)(ws + 10560);
    int*       loO    = (int*)(ws + 10880);
    int*       hiO    = (int*)(ws + 11200);
    float*     melfTe = (float*)(ws + 11520);
    float*     melfTo = (float*)(ws + 53760);
    _Float16*  Bhe    = (_Float16*)(ws + 96256);
    _Float16*  Ble    = (_Float16*)(ws + 227328);
    _Float16*  Bho    = (_Float16*)(ws + 358400);
    _Float16*  Blo    = (_Float16*)(ws + 489472);

    FbankWrapper_14285061226526_kernel<<<10, 256, 0, stream>>>(means);
    k_prep<<<144, 256, 0, stream>>>(melf, dcos, dsin, loE, hiE, loO, hiO,
                                    melfTe, melfTo, Bhe, Ble, Bho, Blo);
    k_main_pre<<<2998, 512, 0, stream>>>(wav, window, melfTe, melfTo,
                                         loE, hiE, loO, hiO,
                                         Bhe, Ble, Bho, Blo, out);
    k_mean<<<dim3(8, BATCH), 256, 0, stream>>>(out, means);
    k_norm<<<dim3((NFRAMES * NMEL + 255) / 256, BATCH), 256, 0, stream>>>(means, out);
}